// Round 1
// 698.409 us; speedup vs baseline: 1.0270x; 1.0270x over previous
//
#include <hip/hip_runtime.h>
#include <math.h>

// Problem constants
#define B_     32
#define T_     512
#define LATENT 64
#define COND   448
#define HIDDEN 1024
#define OUTD   512
#define E_     8
#define INPUT_ 512     // LATENT + COND
#define INTER_ 1536    // LATENT + COND + HIDDEN
#define GATEH  64
#define NTOK   (B_ * T_)   // 16384
#define KTAIL  32          // bias-mix folded into K as one extra 32-chunk

typedef __attribute__((ext_vector_type(8))) short short8;   // bf16x8 MFMA A/B frag
typedef __attribute__((ext_vector_type(4))) float f32x4;    // MFMA C/D frag

static __device__ __forceinline__ unsigned short f2bf(float x) {
    unsigned u = __float_as_uint(x);
    u += 0x7fffu + ((u >> 16) & 1u);
    return (unsigned short)(u >> 16);
}

// ---------------------------------------------------------------------------
// wprep: transpose gate weights to bf16 [n][k] rows for MFMA B-operands.
// gw0T: 64 x 512, gw1T: 64 x 64.
// ---------------------------------------------------------------------------
__global__ __launch_bounds__(256) void wprep_kernel(
    const float* __restrict__ gw0, const float* __restrict__ gw1,
    unsigned short* __restrict__ gw0T, unsigned short* __restrict__ gw1T)
{
    int idx = blockIdx.x * 256 + threadIdx.x;
    if (idx < GATEH * INPUT_) {
        int n = idx >> 9, k = idx & 511;
        gw0T[n * INPUT_ + k] = f2bf(gw0[k * GATEH + n]);
    } else {
        int i2 = idx - GATEH * INPUT_;
        if (i2 < GATEH * GATEH) {
            int n = i2 >> 6, k = i2 & 63;
            gw1T[n * GATEH + k] = f2bf(gw1[k * GATEH + n]);
        }
    }
}

// ---------------------------------------------------------------------------
// Gate (MFMA): 64 tokens/block, 256 threads (4 waves).
// ---------------------------------------------------------------------------
__global__ __launch_bounds__(256) void gate_kernel(
    const float* __restrict__ z, const float* __restrict__ c,
    const float* __restrict__ gb0,
    const float* __restrict__ gb1,
    const float* __restrict__ gw2, const float* __restrict__ gb2,
    const unsigned short* __restrict__ gw0T,
    const unsigned short* __restrict__ gw1T,
    float* __restrict__ coef, unsigned short* __restrict__ coefpad,
    unsigned short* __restrict__ xzb)
{
    __shared__ unsigned short Hb[GATEH][72];   // g0 out, bf16, pad->2-way free
    __shared__ float H2[GATEH][65];            // g1 out, fp32
    __shared__ float sLg[GATEH][E_];           // logits

    const int tid = threadIdx.x;
    const int lane = tid & 63;
    const int wv = tid >> 6;
    const int tok0 = blockIdx.x * 64;

    // ---- phase 0: z|c -> xz bf16 ----
#pragma unroll
    for (int i = 0; i < 4; ++i) {              // z: 64 tok x 64
        int idx = i * 256 + tid;
        int tr = idx >> 4, c4 = (idx & 15) * 4;
        float4 v = *(const float4*)(z + ((size_t)(tok0 + tr) * LATENT) + c4);
        ushort4 o = {f2bf(v.x), f2bf(v.y), f2bf(v.z), f2bf(v.w)};
        *(ushort4*)(xzb + (size_t)(tok0 + tr) * INPUT_ + c4) = o;
    }
#pragma unroll
    for (int i = 0; i < 28; ++i) {             // c: 64 tok x 448
        int idx = i * 256 + tid;
        int tr = idx / 112, c4 = (idx % 112) * 4;
        float4 v = *(const float4*)(c + ((size_t)(tok0 + tr) * COND) + c4);
        ushort4 o = {f2bf(v.x), f2bf(v.y), f2bf(v.z), f2bf(v.w)};
        *(ushort4*)(xzb + (size_t)(tok0 + tr) * INPUT_ + LATENT + c4) = o;
    }
    __threadfence_block();
    __syncthreads();

    const int fr = lane & 15, fq = lane >> 4;
    const int wm0 = (wv & 1) * 32, wn0 = (wv >> 1) * 32;

    // ---- g0 MFMA ----
    f32x4 acc[2][2];
#pragma unroll
    for (int im = 0; im < 2; ++im)
#pragma unroll
        for (int in = 0; in < 2; ++in) acc[im][in] = (f32x4){0.f,0.f,0.f,0.f};

    for (int k0 = 0; k0 < INPUT_; k0 += 32) {
        short8 af[2], bf[2];
#pragma unroll
        for (int im = 0; im < 2; ++im)
            af[im] = *(const short8*)(xzb + (size_t)(tok0 + wm0 + im*16 + fr) * INPUT_
                                          + k0 + fq * 8);
#pragma unroll
        for (int in = 0; in < 2; ++in)
            bf[in] = *(const short8*)(gw0T + (size_t)(wn0 + in*16 + fr) * INPUT_
                                           + k0 + fq * 8);
#pragma unroll
        for (int im = 0; im < 2; ++im)
#pragma unroll
            for (int in = 0; in < 2; ++in)
                acc[im][in] = __builtin_amdgcn_mfma_f32_16x16x32_bf16(
                    af[im], bf[in], acc[im][in], 0, 0, 0);
    }
    // C layout: col=lane&15, row=(lane>>4)*4+reg
#pragma unroll
    for (int im = 0; im < 2; ++im)
#pragma unroll
        for (int in = 0; in < 2; ++in)
#pragma unroll
            for (int reg = 0; reg < 4; ++reg) {
                int m = wm0 + im*16 + fq*4 + reg;
                int n = wn0 + in*16 + fr;
                float h = acc[im][in][reg] + gb0[n];
                h = h > 0.f ? h : 0.01f * h;
                Hb[m][n] = f2bf(h);
            }
    __syncthreads();

    // ---- g1 MFMA ----
    f32x4 a2[2][2];
#pragma unroll
    for (int im = 0; im < 2; ++im)
#pragma unroll
        for (int in = 0; in < 2; ++in) a2[im][in] = (f32x4){0.f,0.f,0.f,0.f};
#pragma unroll
    for (int k0 = 0; k0 < GATEH; k0 += 32) {
        short8 af[2], bf[2];
#pragma unroll
        for (int im = 0; im < 2; ++im)
            af[im] = *(const short8*)(&Hb[wm0 + im*16 + fr][k0 + fq*8]);
#pragma unroll
        for (int in = 0; in < 2; ++in)
            bf[in] = *(const short8*)(gw1T + (size_t)(wn0 + in*16 + fr) * GATEH
                                           + k0 + fq * 8);
#pragma unroll
        for (int im = 0; im < 2; ++im)
#pragma unroll
            for (int in = 0; in < 2; ++in)
                a2[im][in] = __builtin_amdgcn_mfma_f32_16x16x32_bf16(
                    af[im], bf[in], a2[im][in], 0, 0, 0);
    }
#pragma unroll
    for (int im = 0; im < 2; ++im)
#pragma unroll
        for (int in = 0; in < 2; ++in)
#pragma unroll
            for (int reg = 0; reg < 4; ++reg) {
                int m = wm0 + im*16 + fq*4 + reg;
                int n = wn0 + in*16 + fr;
                float h = a2[im][in][reg] + gb1[n];
                H2[m][n] = h > 0.f ? h : 0.01f * h;
            }
    __syncthreads();

    // ---- g2 (vector): thread -> (tok = tid>>2, 2 experts) ----
    {
        int tok = tid >> 2, e0 = (tid & 3) * 2;
        float l0 = gb2[e0], l1 = gb2[e0 + 1];
#pragma unroll
        for (int i = 0; i < GATEH; ++i) {
            float h = H2[tok][i];
            l0 = fmaf(h, gw2[i * E_ + e0], l0);
            l1 = fmaf(h, gw2[i * E_ + e0 + 1], l1);
        }
        sLg[tok][e0] = l0; sLg[tok][e0 + 1] = l1;
    }
    __syncthreads();

    // ---- softmax + outputs: one thread per token ----
    if (tid < 64) {
        int token = tok0 + tid;
        float lg[E_], m = -1e30f, s = 0.f;
#pragma unroll
        for (int e = 0; e < E_; ++e) { lg[e] = sLg[tid][e]; m = fmaxf(m, lg[e]); }
#pragma unroll
        for (int e = 0; e < E_; ++e) { lg[e] = expf(lg[e] - m); s += lg[e]; }
        float inv = 1.f / s;
        unsigned short pad[KTAIL];
#pragma unroll
        for (int e = 0; e < E_; ++e) {
            float cv = lg[e] * inv;
            coef[(size_t)token * E_ + e] = cv;
            pad[e] = f2bf(cv);
        }
#pragma unroll
        for (int j = E_; j < KTAIL; ++j) pad[j] = 0;
#pragma unroll
        for (int q = 0; q < 4; ++q)
            *(ushort4*)(coefpad + (size_t)token * KTAIL + q * 4) =
                *(const ushort4*)&pad[q * 4];
    }
}

// ---------------------------------------------------------------------------
// Transpose-mix: wmT[b][o][i] = bf16( sum_e coef0[batch0+b][e] * w[e][i][o] )
// for i < fin; K-tail rows i in [fin, fin+32): bias[e][o] (e<8) else 0.
// ---------------------------------------------------------------------------
#define MI 32
#define MO 64
#define MP 65

__global__ __launch_bounds__(256) void mixT_kernel(
    const float* __restrict__ w,          // (E, fin, fout) fp32
    const float* __restrict__ bias,       // (E, fout) fp32
    const float* __restrict__ coef,       // (NTOK, 8)
    unsigned short* __restrict__ wmT,     // (gb, fout, fin+32) bf16
    int fin, int fout, int gb, int batch0)
{
    __shared__ float sW[E_][MI][MP];
    __shared__ float sC[B_][E_];
    const int t = threadIdx.x;
    const int fin_tot = fin + KTAIL;
    const int nbi = fin / MI;
    const int i0 = (blockIdx.x % nbi) * MI;
    const int o0 = (blockIdx.x / nbi) * MO;

    if (t < gb * E_)
        sC[t >> 3][t & 7] = coef[(size_t)(batch0 + (t >> 3)) * T_ * E_ + (t & 7)];

#pragma unroll
    for (int r = 0; r < 64; ++r) {
        int idx = r * 256 + t;
        int o = idx & 63;
        int i = (idx >> 6) & 31;
        int e = idx >> 11;
        sW[e][i][o] = w[(size_t)e * fin * fout + (size_t)(i0 + i) * fout + o0 + o];
    }
    __syncthreads();

    const int o  = t >> 2;
    const int i8 = (t & 3) * 8;
    for (int b = 0; b < gb; ++b) {
        float v[8];
#pragma unroll
        for (int j = 0; j < 8; ++j) v[j] = 0.f;
#pragma unroll
        for (int e = 0; e < E_; ++e) {
            float cc = sC[b][e];
#pragma unroll
            for (int j = 0; j < 8; ++j)
                v[j] = fmaf(cc, sW[e][i8 + j][o], v[j]);
        }
        unsigned short u[8];
#pragma unroll
        for (int j = 0; j < 8; ++j) u[j] = f2bf(v[j]);
        *(int4*)(wmT + ((size_t)b * fout + o0 + o) * fin_tot + i0 + i8) = *(const int4*)u;
    }

    if (i0 == 0) {
        const int jj = t & 3;
        unsigned short u[8];
#pragma unroll
        for (int q = 0; q < 8; ++q)
            u[q] = (jj == 0) ? f2bf(bias[(size_t)q * fout + o0 + o]) : 0;
        for (int b = 0; b < gb; ++b)
            *(int4*)(wmT + ((size_t)b * fout + o0 + o) * fin_tot + fin + jj * 8) =
                *(const int4*)u;
    }
}

// ---------------------------------------------------------------------------
// MFMA GEMM, v2: 256x256 tile, BK=32, 512 threads (8 waves, 2M x 4N),
// per-wave 128x64 output (8x4 16x16 frags). 4-deep LDS ring (128 KiB),
// counted s_waitcnt vmcnt(8) -- never 0 in the main loop: each tile's
// global_load_lds is issued 3 iterations before its compute. One barrier
// per K-tile (32 MFMA/wave between barriers). setprio(1) around MFMA.
// XOR-swizzled staging (pre-swizzled global source + swizzled read offset,
// bank-conflict-free; same scheme as v1). Batch-clustered bijective XCD
// remap: all blocks of one batch share one XCD L2 (A-panel + wmT reuse).
// ---------------------------------------------------------------------------
__global__ __launch_bounds__(512, 2) void gemm_kernel(
    const unsigned short* __restrict__ xz,      // (NTOK, 512) bf16
    const unsigned short* __restrict__ prev,    // (NTOK, 1024) bf16
    const unsigned short* __restrict__ wmT,     // (gb, fout, fin_tot) bf16
    const unsigned short* __restrict__ coefpad, // (NTOK, 32) bf16
    float* __restrict__ outf,                   // fp32 out (layer 4)
    unsigned short* __restrict__ outb,          // bf16 out (layers 0-3), or null
    int fin_tot, int fout, int act, int batch0)
{
    __shared__ __align__(16) unsigned short As[4][8192];   // 4 x 16 KB
    __shared__ __align__(16) unsigned short Bs[4][8192];   // 4 x 16 KB

    const int tid = threadIdx.x;
    const int lane = tid & 63;
    const int w8 = tid >> 6;          // wave 0..7
    const int wm = w8 & 1;            // M half
    const int wn = w8 >> 1;           // N quarter

    // ---- batch-clustered XCD remap (bijective when 8 | nwg) ----
    const int nx = gridDim.x;         // fout/256
    int bx = blockIdx.x, by = blockIdx.y, bz = blockIdx.z;
    {
        int nwg = nx * 2 * gridDim.z;
        if ((nwg & 7) == 0) {
            int f = blockIdx.x + nx * (blockIdx.y + 2 * blockIdx.z);
            int q = nwg >> 3;
            int wk = (f & 7) * q + (f >> 3);   // XCD (f&7) owns contiguous chunk
            int bpb = nx * 2;                  // blocks per batch
            bz = wk / bpb;
            int r = wk - bz * bpb;
            by = r / nx;
            bx = r - by * nx;
        }
    }

    const int row0 = by * 256;
    const int col0 = bx * 256;
    const size_t tokbase = (size_t)(batch0 + bz) * T_;
    const unsigned short* wmb = wmT + (size_t)bz * fin_tot * fout;

    // staging lane geometry (matches global_load_lds linear lane scatter)
    const int lrow = lane >> 2;                               // row in 16-row chunk
    const int lk8  = (((lane & 3) ^ ((lane >> 3) & 3)) * 8);  // swizzled k offset
    // frag-read geometry
    const int fr = lane & 15, fq = lane >> 4;
    const int koff = (fq ^ ((fr >> 1) & 3)) * 8;              // swizzled read offset
    const int ktail0 = fin_tot - KTAIL;
    const int nt = fin_tot >> 5;                              // 17 or 49 K-tiles

    f32x4 acc[8][4];
#pragma unroll
    for (int im = 0; im < 8; ++im)
#pragma unroll
        for (int in = 0; in < 4; ++in)
            acc[im][in] = (f32x4){0.f, 0.f, 0.f, 0.f};

    // stage K-tile t into ring slot t&3: 4 global_load_lds per thread
    auto stage = [&](int t) {
        int k0 = t << 5;
        const unsigned short* abase; int astr, acol;
        if (k0 < INPUT_)      { abase = xz;      astr = INPUT_; acol = k0; }
        else if (k0 < ktail0) { abase = prev;    astr = HIDDEN; acol = k0 - INPUT_; }
        else                  { abase = coefpad; astr = KTAIL;  acol = 0; }
        unsigned short* Ab = As[t & 3];
        unsigned short* Bb = Bs[t & 3];
#pragma unroll
        for (int j = 0; j < 2; ++j) {
            int ch = w8 + 8 * j;                // chunk 0..15 (wave-uniform)
            const unsigned short* srcA = abase
                + (tokbase + row0 + ch * 16 + lrow) * (size_t)astr + acol + lk8;
            __builtin_amdgcn_global_load_lds(
                (const __attribute__((address_space(1))) unsigned int*)(const void*)srcA,
                (__attribute__((address_space(3))) unsigned int*)(void*)(Ab + ch * 512),
                16, 0, 0);
            const unsigned short* srcB = wmb
                + (size_t)(col0 + ch * 16 + lrow) * fin_tot + k0 + lk8;
            __builtin_amdgcn_global_load_lds(
                (const __attribute__((address_space(1))) unsigned int*)(const void*)srcB,
                (__attribute__((address_space(3))) unsigned int*)(void*)(Bb + ch * 512),
                16, 0, 0);
        }
    };

    // prologue: 3 tiles in flight
    stage(0);
    if (nt > 1) stage(1);
    if (nt > 2) stage(2);

    for (int t = 0; t < nt; ++t) {
        // wait for tile t only; tiles t+1, t+2 stay in flight (counted vmcnt)
        int rem = nt - 1 - t;
        if (rem >= 2)
            asm volatile("s_waitcnt vmcnt(8)\n\ts_barrier" ::: "memory");
        else if (rem == 1)
            asm volatile("s_waitcnt vmcnt(4)\n\ts_barrier" ::: "memory");
        else
            asm volatile("s_waitcnt vmcnt(0)\n\ts_barrier" ::: "memory");

        // prefetch 3 tiles ahead into the slot freed by tile t-1
        if (t + 3 < nt) stage(t + 3);

        const unsigned short* Ab = As[t & 3] + wm * 4096;   // wave's 8 A chunks
        const unsigned short* Bb = Bs[t & 3] + wn * 2048;   // wave's 4 B chunks
        short8 af[8], bfv[4];
#pragma unroll
        for (int im = 0; im < 8; ++im)
            af[im] = *(const short8*)(Ab + im * 512 + fr * 32 + koff);
#pragma unroll
        for (int in = 0; in < 4; ++in)
            bfv[in] = *(const short8*)(Bb + in * 512 + fr * 32 + koff);

        __builtin_amdgcn_s_setprio(1);
#pragma unroll
        for (int im = 0; im < 8; ++im)
#pragma unroll
            for (int in = 0; in < 4; ++in)
                acc[im][in] = __builtin_amdgcn_mfma_f32_16x16x32_bf16(
                    af[im], bfv[in], acc[im][in], 0, 0, 0);
        __builtin_amdgcn_s_setprio(0);
    }

    // epilogue: C/D layout col=lane&15, row=quad*4+reg; leaky + store
#pragma unroll
    for (int im = 0; im < 8; ++im) {
#pragma unroll
        for (int in = 0; in < 4; ++in) {
#pragma unroll
            for (int reg = 0; reg < 4; ++reg) {
                int r = wm * 128 + im * 16 + fq * 4 + reg;
                int col = wn * 64 + in * 16 + fr;
                float v = acc[im][in][reg];
                if (act) v = v > 0.f ? v : 0.01f * v;
                size_t off = (tokbase + row0 + r) * fout + col0 + col;
                if (outb) outb[off] = f2bf(v);
                else      outf[off] = v;
            }
        }
    }
}

// ---------------------------------------------------------------------------
// Launch. Workspace: gw0T 64K | gw1T 8K | xz 16.8M | coef 0.5M | cpad 1M |
// actB 33.6M (base ~52.0M); then adaptive gb tier for wmT (+actA at gb=32).
// ---------------------------------------------------------------------------
extern "C" void kernel_launch(void* const* d_in, const int* in_sizes, int n_in,
                              void* d_out, int out_size, void* d_ws, size_t ws_size,
                              hipStream_t stream)
{
    const float* z = (const float*)d_in[0];
    const float* c = (const float*)d_in[1];
    const float* w[5]  = {(const float*)d_in[2], (const float*)d_in[4],
                          (const float*)d_in[6], (const float*)d_in[8],
                          (const float*)d_in[10]};
    const float* bs[5] = {(const float*)d_in[3], (const float*)d_in[5],
                          (const float*)d_in[7], (const float*)d_in[9],
                          (const float*)d_in[11]};
    const float* gw0 = (const float*)d_in[12]; const float* gb0 = (const float*)d_in[13];
    const float* gw1 = (const float*)d_in[14]; const float* gb1 = (const float*)d_in[15];
    const float* gw2 = (const float*)d_in[16]; const float* gb2 = (const float*)d_in[17];

    const size_t g0t_b  = (size_t)GATEH * INPUT_ * 2;   // 64 KB
    const size_t g1t_b  = (size_t)GATEH * GATEH * 2;    // 8 KB
    const size_t xz_b   = (size_t)NTOK * INPUT_ * 2;
    const size_t coef_b = (size_t)NTOK * E_ * 4;
    const size_t cpad_b = (size_t)NTOK * KTAIL * 2;
    const size_t act_b  = (size_t)NTOK * HIDDEN * 2;
    const size_t wmun   = (size_t)(INTER_ + KTAIL) * HIDDEN * 2;  // per-batch max

    char* p = (char*)d_ws;
    unsigned short* gw0T  = (unsigned short*)p;  p += g0t_b;
    unsigned short* gw1T  = (unsigned short*)p;  p += g1t_b;
    unsigned short* xzb   = (unsigned short*)p;  p += xz_b;
    float*          coef  = (float*)p;           p += coef_b;
    unsigned short* cpad  = (unsigned short*)p;  p += cpad_b;
    unsigned short* actB  = (unsigned short*)p;  p += act_b;

    size_t base = g0t_b + g1t_b + xz_b + coef_b + cpad_b + act_b;
    size_t avail = (ws_size > base) ? ws_size - base : 0;

    int gb;
    unsigned short* actA;
    unsigned short* wmT;
    if (avail >= act_b + 32 * wmun) {
        gb = 32; actA = (unsigned short*)p; p += act_b; wmT = (unsigned short*)p;
    } else {
        actA = (unsigned short*)d_out;
        wmT  = (unsigned short*)p;
        gb = 1;
        for (int g = 16; g >= 2; g >>= 1)
            if (avail >= (size_t)g * wmun) { gb = g; break; }
    }

    wprep_kernel<<<(GATEH * (INPUT_ + GATEH) + 255) / 256, 256, 0, stream>>>(
        gw0, gw1, gw0T, gw1T);
    gate_kernel<<<NTOK / 64, 256, 0, stream>>>(
        z, c, gb0, gb1, gw2, gb2, gw0T, gw1T, coef, cpad, xzb);

    struct L { int fin, fout, act; const unsigned short* in; unsigned short* outb; };
    L Ls[5] = {
        {INPUT_, HIDDEN, 1, actB /*unused*/, actA},
        {INTER_, HIDDEN, 1, actA, actB},
        {INTER_, HIDDEN, 1, actB, actA},
        {INTER_, HIDDEN, 1, actA, actB},
        {INTER_, OUTD,   0, actB, 0},
    };

    for (int Li = 0; Li < 5; ++Li) {
        int fin = Ls[Li].fin, fout = Ls[Li].fout;
        int nblk = (fin / MI) * (fout / MO);
        for (int g = 0; g < B_; g += gb) {
            mixT_kernel<<<nblk, 256, 0, stream>>>(
                w[Li], bs[Li], coef, wmT, fin, fout, gb, g);
            gemm_kernel<<<dim3(fout / 256, T_ / 256, gb), 512, 0, stream>>>(
                xzb, Ls[Li].in, wmT, cpad,
                (float*)d_out, Ls[Li].outb, fin + KTAIL, fout, Ls[Li].act, g);
        }
    }
}

// Round 2
// 685.095 us; speedup vs baseline: 1.0469x; 1.0194x over previous
//
#include <hip/hip_runtime.h>
#include <math.h>

// Problem constants
#define B_     32
#define T_     512
#define LATENT 64
#define COND   448
#define HIDDEN 1024
#define OUTD   512
#define E_     8
#define INPUT_ 512     // LATENT + COND
#define INTER_ 1536    // LATENT + COND + HIDDEN
#define GATEH  64
#define NTOK   (B_ * T_)   // 16384
#define KTAIL  64          // bias-mix folded into K as one extra 64-chunk (BK=64 aligned)

typedef __attribute__((ext_vector_type(8))) short short8;   // bf16x8 MFMA A/B frag
typedef __attribute__((ext_vector_type(4))) float f32x4;    // MFMA C/D frag

static __device__ __forceinline__ unsigned short f2bf(float x) {
    unsigned u = __float_as_uint(x);
    u += 0x7fffu + ((u >> 16) & 1u);
    return (unsigned short)(u >> 16);
}

// ---------------------------------------------------------------------------
// wprep: transpose gate weights to bf16 [n][k] rows for MFMA B-operands.
// ---------------------------------------------------------------------------
__global__ __launch_bounds__(256) void wprep_kernel(
    const float* __restrict__ gw0, const float* __restrict__ gw1,
    unsigned short* __restrict__ gw0T, unsigned short* __restrict__ gw1T)
{
    int idx = blockIdx.x * 256 + threadIdx.x;
    if (idx < GATEH * INPUT_) {
        int n = idx >> 9, k = idx & 511;
        gw0T[n * INPUT_ + k] = f2bf(gw0[k * GATEH + n]);
    } else {
        int i2 = idx - GATEH * INPUT_;
        if (i2 < GATEH * GATEH) {
            int n = i2 >> 6, k = i2 & 63;
            gw1T[n * GATEH + k] = f2bf(gw1[k * GATEH + n]);
        }
    }
}

// ---------------------------------------------------------------------------
// Gate (MFMA): 64 tokens/block, 256 threads (4 waves).
// ---------------------------------------------------------------------------
__global__ __launch_bounds__(256) void gate_kernel(
    const float* __restrict__ z, const float* __restrict__ c,
    const float* __restrict__ gb0,
    const float* __restrict__ gb1,
    const float* __restrict__ gw2, const float* __restrict__ gb2,
    const unsigned short* __restrict__ gw0T,
    const unsigned short* __restrict__ gw1T,
    float* __restrict__ coef, unsigned short* __restrict__ coefpad,
    unsigned short* __restrict__ xzb)
{
    __shared__ unsigned short Hb[GATEH][72];   // g0 out, bf16, pad->2-way free
    __shared__ float H2[GATEH][65];            // g1 out, fp32
    __shared__ float sLg[GATEH][E_];           // logits

    const int tid = threadIdx.x;
    const int lane = tid & 63;
    const int wv = tid >> 6;
    const int tok0 = blockIdx.x * 64;

    // ---- phase 0: z|c -> xz bf16 ----
#pragma unroll
    for (int i = 0; i < 4; ++i) {              // z: 64 tok x 64
        int idx = i * 256 + tid;
        int tr = idx >> 4, c4 = (idx & 15) * 4;
        float4 v = *(const float4*)(z + ((size_t)(tok0 + tr) * LATENT) + c4);
        ushort4 o = {f2bf(v.x), f2bf(v.y), f2bf(v.z), f2bf(v.w)};
        *(ushort4*)(xzb + (size_t)(tok0 + tr) * INPUT_ + c4) = o;
    }
#pragma unroll
    for (int i = 0; i < 28; ++i) {             // c: 64 tok x 448
        int idx = i * 256 + tid;
        int tr = idx / 112, c4 = (idx % 112) * 4;
        float4 v = *(const float4*)(c + ((size_t)(tok0 + tr) * COND) + c4);
        ushort4 o = {f2bf(v.x), f2bf(v.y), f2bf(v.z), f2bf(v.w)};
        *(ushort4*)(xzb + (size_t)(tok0 + tr) * INPUT_ + LATENT + c4) = o;
    }
    __threadfence_block();
    __syncthreads();

    const int fr = lane & 15, fq = lane >> 4;
    const int wm0 = (wv & 1) * 32, wn0 = (wv >> 1) * 32;

    // ---- g0 MFMA ----
    f32x4 acc[2][2];
#pragma unroll
    for (int im = 0; im < 2; ++im)
#pragma unroll
        for (int in = 0; in < 2; ++in) acc[im][in] = (f32x4){0.f,0.f,0.f,0.f};

    for (int k0 = 0; k0 < INPUT_; k0 += 32) {
        short8 af[2], bf[2];
#pragma unroll
        for (int im = 0; im < 2; ++im)
            af[im] = *(const short8*)(xzb + (size_t)(tok0 + wm0 + im*16 + fr) * INPUT_
                                          + k0 + fq * 8);
#pragma unroll
        for (int in = 0; in < 2; ++in)
            bf[in] = *(const short8*)(gw0T + (size_t)(wn0 + in*16 + fr) * INPUT_
                                           + k0 + fq * 8);
#pragma unroll
        for (int im = 0; im < 2; ++im)
#pragma unroll
            for (int in = 0; in < 2; ++in)
                acc[im][in] = __builtin_amdgcn_mfma_f32_16x16x32_bf16(
                    af[im], bf[in], acc[im][in], 0, 0, 0);
    }
    // C layout: col=lane&15, row=(lane>>4)*4+reg
#pragma unroll
    for (int im = 0; im < 2; ++im)
#pragma unroll
        for (int in = 0; in < 2; ++in)
#pragma unroll
            for (int reg = 0; reg < 4; ++reg) {
                int m = wm0 + im*16 + fq*4 + reg;
                int n = wn0 + in*16 + fr;
                float h = acc[im][in][reg] + gb0[n];
                h = h > 0.f ? h : 0.01f * h;
                Hb[m][n] = f2bf(h);
            }
    __syncthreads();

    // ---- g1 MFMA ----
    f32x4 a2[2][2];
#pragma unroll
    for (int im = 0; im < 2; ++im)
#pragma unroll
        for (int in = 0; in < 2; ++in) a2[im][in] = (f32x4){0.f,0.f,0.f,0.f};
#pragma unroll
    for (int k0 = 0; k0 < GATEH; k0 += 32) {
        short8 af[2], bf[2];
#pragma unroll
        for (int im = 0; im < 2; ++im)
            af[im] = *(const short8*)(&Hb[wm0 + im*16 + fr][k0 + fq*8]);
#pragma unroll
        for (int in = 0; in < 2; ++in)
            bf[in] = *(const short8*)(gw1T + (size_t)(wn0 + in*16 + fr) * GATEH
                                           + k0 + fq * 8);
#pragma unroll
        for (int im = 0; im < 2; ++im)
#pragma unroll
            for (int in = 0; in < 2; ++in)
                a2[im][in] = __builtin_amdgcn_mfma_f32_16x16x32_bf16(
                    af[im], bf[in], a2[im][in], 0, 0, 0);
    }
#pragma unroll
    for (int im = 0; im < 2; ++im)
#pragma unroll
        for (int in = 0; in < 2; ++in)
#pragma unroll
            for (int reg = 0; reg < 4; ++reg) {
                int m = wm0 + im*16 + fq*4 + reg;
                int n = wn0 + in*16 + fr;
                float h = a2[im][in][reg] + gb1[n];
                H2[m][n] = h > 0.f ? h : 0.01f * h;
            }
    __syncthreads();

    // ---- g2 (vector): thread -> (tok = tid>>2, 2 experts) ----
    {
        int tok = tid >> 2, e0 = (tid & 3) * 2;
        float l0 = gb2[e0], l1 = gb2[e0 + 1];
#pragma unroll
        for (int i = 0; i < GATEH; ++i) {
            float h = H2[tok][i];
            l0 = fmaf(h, gw2[i * E_ + e0], l0);
            l1 = fmaf(h, gw2[i * E_ + e0 + 1], l1);
        }
        sLg[tok][e0] = l0; sLg[tok][e0 + 1] = l1;
    }
    __syncthreads();

    // ---- softmax + outputs: one thread per token ----
    if (tid < 64) {
        int token = tok0 + tid;
        float lg[E_], m = -1e30f, s = 0.f;
#pragma unroll
        for (int e = 0; e < E_; ++e) { lg[e] = sLg[tid][e]; m = fmaxf(m, lg[e]); }
#pragma unroll
        for (int e = 0; e < E_; ++e) { lg[e] = expf(lg[e] - m); s += lg[e]; }
        float inv = 1.f / s;
        unsigned short pad[KTAIL];
#pragma unroll
        for (int e = 0; e < E_; ++e) {
            float cv = lg[e] * inv;
            coef[(size_t)token * E_ + e] = cv;
            pad[e] = f2bf(cv);
        }
#pragma unroll
        for (int j = E_; j < KTAIL; ++j) pad[j] = 0;
#pragma unroll
        for (int q = 0; q < KTAIL / 4; ++q)
            *(ushort4*)(coefpad + (size_t)token * KTAIL + q * 4) =
                *(const ushort4*)&pad[q * 4];
    }
}

// ---------------------------------------------------------------------------
// Transpose-mix: wmT[b][o][i] = bf16( sum_e coef0[batch0+b][e] * w[e][i][o] )
// for i < fin; K-tail rows i in [fin, fin+8): bias[e][o]; [fin+8,fin+64): 0.
// ---------------------------------------------------------------------------
#define MI 32
#define MO 64
#define MP 65

__global__ __launch_bounds__(256) void mixT_kernel(
    const float* __restrict__ w,          // (E, fin, fout) fp32
    const float* __restrict__ bias,       // (E, fout) fp32
    const float* __restrict__ coef,       // (NTOK, 8)
    unsigned short* __restrict__ wmT,     // (gb, fout, fin+64) bf16
    int fin, int fout, int gb, int batch0)
{
    __shared__ float sW[E_][MI][MP];
    __shared__ float sC[B_][E_];
    const int t = threadIdx.x;
    const int fin_tot = fin + KTAIL;
    const int nbi = fin / MI;
    const int i0 = (blockIdx.x % nbi) * MI;
    const int o0 = (blockIdx.x / nbi) * MO;

    if (t < gb * E_)
        sC[t >> 3][t & 7] = coef[(size_t)(batch0 + (t >> 3)) * T_ * E_ + (t & 7)];

#pragma unroll
    for (int r = 0; r < 64; ++r) {
        int idx = r * 256 + t;
        int o = idx & 63;
        int i = (idx >> 6) & 31;
        int e = idx >> 11;
        sW[e][i][o] = w[(size_t)e * fin * fout + (size_t)(i0 + i) * fout + o0 + o];
    }
    __syncthreads();

    const int o  = t >> 2;
    const int i8 = (t & 3) * 8;
    for (int b = 0; b < gb; ++b) {
        float v[8];
#pragma unroll
        for (int j = 0; j < 8; ++j) v[j] = 0.f;
#pragma unroll
        for (int e = 0; e < E_; ++e) {
            float cc = sC[b][e];
#pragma unroll
            for (int j = 0; j < 8; ++j)
                v[j] = fmaf(cc, sW[e][i8 + j][o], v[j]);
        }
        unsigned short u[8];
#pragma unroll
        for (int j = 0; j < 8; ++j) u[j] = f2bf(v[j]);
        *(int4*)(wmT + ((size_t)b * fout + o0 + o) * fin_tot + i0 + i8) = *(const int4*)u;
    }

    if (i0 == 0) {
        const int jj = t & 3;
        unsigned short u[8];
#pragma unroll
        for (int q = 0; q < 8; ++q)
            u[q] = (jj == 0) ? f2bf(bias[(size_t)q * fout + o0 + o]) : 0;
        unsigned short z8[8] = {0, 0, 0, 0, 0, 0, 0, 0};
        for (int b = 0; b < gb; ++b) {
            size_t rb = ((size_t)b * fout + o0 + o) * fin_tot + fin;
            *(int4*)(wmT + rb + jj * 8)      = *(const int4*)u;
            *(int4*)(wmT + rb + 32 + jj * 8) = *(const int4*)z8;
        }
    }
}

// ---------------------------------------------------------------------------
// MFMA GEMM, v3: m201-style 8-phase schedule. 256x256 tile, BK=64, 512 thr
// (8 waves 2Mx4N, per-wave 128x64 = 8x4 frags). Double-buffered LDS 128 KiB:
// As/Bs[buf][kk][16 chunks * 512]. Per K-tile: 4 phases x {4-8 ds_read_b128,
// stage one 16KB half-tile (2 gload_lds), barrier, lgkmcnt(0), setprio(1),
// 16 MFMA, setprio(0), barrier}. Counted vmcnt(4) only at phases 1 and 3 --
// never 0 in the main loop; every staged half has >= 3 phases of lead.
// XOR-swizzled staging (pre-swizzled global source, conflict-free reads).
// Batch-clustered bijective XCD remap.
// ---------------------------------------------------------------------------
__global__ __launch_bounds__(512, 2) void gemm_kernel(
    const unsigned short* __restrict__ xz,      // (NTOK, 512) bf16
    const unsigned short* __restrict__ prev,    // (NTOK, 1024) bf16
    const unsigned short* __restrict__ wmT,     // (gb, fout, fin_tot) bf16
    const unsigned short* __restrict__ coefpad, // (NTOK, 64) bf16
    float* __restrict__ outf,                   // fp32 out (layer 4)
    unsigned short* __restrict__ outb,          // bf16 out (layers 0-3), or null
    int fin_tot, int fout, int act, int batch0)
{
    __shared__ __align__(16) unsigned short As[2][2][8192];   // 64 KiB
    __shared__ __align__(16) unsigned short Bs[2][2][8192];   // 64 KiB

    const int tid = threadIdx.x;
    const int lane = tid & 63;
    const int w8 = tid >> 6;          // wave 0..7
    const int wm = w8 & 1;            // M half
    const int wn = w8 >> 1;           // N quarter

    // ---- batch-clustered XCD remap (bijective when 8 | nwg) ----
    const int nx = gridDim.x;         // fout/256
    int bx = blockIdx.x, by = blockIdx.y, bz = blockIdx.z;
    {
        int nwg = nx * 2 * gridDim.z;
        if ((nwg & 7) == 0) {
            int f = blockIdx.x + nx * (blockIdx.y + 2 * blockIdx.z);
            int q = nwg >> 3;
            int wk = (f & 7) * q + (f >> 3);   // XCD (f&7) owns contiguous chunk
            int bpb = nx * 2;                  // blocks per batch
            bz = wk / bpb;
            int r = wk - bz * bpb;
            by = r / nx;
            bx = r - by * nx;
        }
    }

    const int row0 = by * 256;
    const int col0 = bx * 256;
    const size_t tokbase = (size_t)(batch0 + bz) * T_;
    const unsigned short* wmb = wmT + (size_t)bz * fin_tot * fout;

    // staging lane geometry (matches global_load_lds linear lane scatter)
    const int lrow = lane >> 2;                               // row in 16-row chunk
    const int lk8  = (((lane & 3) ^ ((lane >> 3) & 3)) * 8);  // swizzled k offset
    // frag-read geometry
    const int fr = lane & 15, fq = lane >> 4;
    const int koff = (fq ^ ((fr >> 1) & 3)) * 8;              // swizzled read offset
    const int ktail0 = fin_tot - KTAIL;
    const int nt = fin_tot >> 6;                              // 9 or 25 K-tiles

    f32x4 acc[8][4];
#pragma unroll
    for (int im = 0; im < 8; ++im)
#pragma unroll
        for (int in = 0; in < 4; ++in)
            acc[im][in] = (f32x4){0.f, 0.f, 0.f, 0.f};

    // stage one A half-tile (256 rows x 32 k, 16 KB) of K-tile t, k-half kk
    auto stageA = [&](int t, int kk) {
        int k32 = (t << 6) + (kk << 5);
        const unsigned short* abase; int astr, acol;
        if (k32 < INPUT_)      { abase = xz;      astr = INPUT_; acol = k32; }
        else if (k32 < ktail0) { abase = prev;    astr = HIDDEN; acol = k32 - INPUT_; }
        else                   { abase = coefpad; astr = KTAIL;  acol = k32 - ktail0; }
        unsigned short* Ab = &As[t & 1][kk][0];
#pragma unroll
        for (int j = 0; j < 2; ++j) {
            int ch = w8 + 8 * j;              // chunk 0..15 (wave-uniform)
            const unsigned short* src = abase
                + (tokbase + row0 + ch * 16 + lrow) * (size_t)astr + acol + lk8;
            __builtin_amdgcn_global_load_lds(
                (const __attribute__((address_space(1))) unsigned int*)(const void*)src,
                (__attribute__((address_space(3))) unsigned int*)(void*)(Ab + ch * 512),
                16, 0, 0);
        }
    };
    auto stageB = [&](int t, int kk) {
        int k32 = (t << 6) + (kk << 5);
        unsigned short* Bb = &Bs[t & 1][kk][0];
#pragma unroll
        for (int j = 0; j < 2; ++j) {
            int ch = w8 + 8 * j;
            const unsigned short* src = wmb
                + (size_t)(col0 + ch * 16 + lrow) * fin_tot + k32 + lk8;
            __builtin_amdgcn_global_load_lds(
                (const __attribute__((address_space(1))) unsigned int*)(const void*)src,
                (__attribute__((address_space(3))) unsigned int*)(void*)(Bb + ch * 512),
                16, 0, 0);
        }
    };

    auto readA4 = [&](const unsigned short* Ak, int im0, short8* af) {
#pragma unroll
        for (int q = 0; q < 4; ++q)
            af[q] = *(const short8*)(Ak + (im0 + q) * 512 + fr * 32 + koff);
    };
    auto readB4 = [&](const unsigned short* Bk, short8* bv) {
#pragma unroll
        for (int q = 0; q < 4; ++q)
            bv[q] = *(const short8*)(Bk + q * 512 + fr * 32 + koff);
    };
    auto mfma16 = [&](int im0, short8* af, short8* bv) {
#pragma unroll
        for (int q = 0; q < 4; ++q)
#pragma unroll
            for (int in = 0; in < 4; ++in)
                acc[im0 + q][in] = __builtin_amdgcn_mfma_f32_16x16x32_bf16(
                    af[q], bv[in], acc[im0 + q][in], 0, 0, 0);
    };

    // ---- prologue: stage tile 0 (order Ak0,Bk0,Ak1,Bk1), wait k0 halves ----
    stageA(0, 0); stageB(0, 0); stageA(0, 1); stageB(0, 1);
    asm volatile("s_waitcnt vmcnt(4)" ::: "memory");
    __builtin_amdgcn_s_barrier();

    // ---- main loop: 4 phases per K-tile ----
    for (int t = 0; t < nt - 1; ++t) {
        const int cur = t & 1;
        const unsigned short* A0  = &As[cur][0][wm * 4096];
        const unsigned short* A1  = &As[cur][1][wm * 4096];
        const unsigned short* Bk0 = &Bs[cur][0][wn * 2048];
        const unsigned short* Bk1 = &Bs[cur][1][wn * 2048];
        short8 af[4], bv[4];

        // phase 0: kk0, im 0-3  (stage A-k0 of t+1)
        readA4(A0, 0, af); readB4(Bk0, bv);
        stageA(t + 1, 0);
        __builtin_amdgcn_s_barrier();
        asm volatile("s_waitcnt lgkmcnt(0)" ::: "memory");
        __builtin_amdgcn_s_setprio(1);
        mfma16(0, af, bv);
        __builtin_amdgcn_s_setprio(0);
        __builtin_amdgcn_s_barrier();

        // phase 1: kk0, im 4-7  (stage B-k0 of t+1; drain k1(t))
        readA4(A0, 4, af);
        stageB(t + 1, 0);
        asm volatile("s_waitcnt vmcnt(4)" ::: "memory");
        __builtin_amdgcn_s_barrier();
        asm volatile("s_waitcnt lgkmcnt(0)" ::: "memory");
        __builtin_amdgcn_s_setprio(1);
        mfma16(4, af, bv);
        __builtin_amdgcn_s_setprio(0);
        __builtin_amdgcn_s_barrier();

        // phase 2: kk1, im 0-3  (stage A-k1 of t+1)
        readA4(A1, 0, af); readB4(Bk1, bv);
        stageA(t + 1, 1);
        __builtin_amdgcn_s_barrier();
        asm volatile("s_waitcnt lgkmcnt(0)" ::: "memory");
        __builtin_amdgcn_s_setprio(1);
        mfma16(0, af, bv);
        __builtin_amdgcn_s_setprio(0);
        __builtin_amdgcn_s_barrier();

        // phase 3: kk1, im 4-7  (stage B-k1 of t+1; drain k0(t+1))
        readA4(A1, 4, af);
        stageB(t + 1, 1);
        asm volatile("s_waitcnt vmcnt(4)" ::: "memory");
        __builtin_amdgcn_s_barrier();
        asm volatile("s_waitcnt lgkmcnt(0)" ::: "memory");
        __builtin_amdgcn_s_setprio(1);
        mfma16(4, af, bv);
        __builtin_amdgcn_s_setprio(0);
        __builtin_amdgcn_s_barrier();
    }

    // ---- final tile: no staging; drain k1 before phase 2 ----
    {
        const int cur = (nt - 1) & 1;
        const unsigned short* A0  = &As[cur][0][wm * 4096];
        const unsigned short* A1  = &As[cur][1][wm * 4096];
        const unsigned short* Bk0 = &Bs[cur][0][wn * 2048];
        const unsigned short* Bk1 = &Bs[cur][1][wn * 2048];
        short8 af[4], bv[4];

        readA4(A0, 0, af); readB4(Bk0, bv);
        __builtin_amdgcn_s_barrier();
        asm volatile("s_waitcnt lgkmcnt(0)" ::: "memory");
        __builtin_amdgcn_s_setprio(1);
        mfma16(0, af, bv);
        __builtin_amdgcn_s_setprio(0);
        __builtin_amdgcn_s_barrier();

        readA4(A0, 4, af);
        asm volatile("s_waitcnt vmcnt(0)" ::: "memory");
        __builtin_amdgcn_s_barrier();
        asm volatile("s_waitcnt lgkmcnt(0)" ::: "memory");
        __builtin_amdgcn_s_setprio(1);
        mfma16(4, af, bv);
        __builtin_amdgcn_s_setprio(0);
        __builtin_amdgcn_s_barrier();

        readA4(A1, 0, af); readB4(Bk1, bv);
        asm volatile("s_waitcnt lgkmcnt(0)" ::: "memory");
        __builtin_amdgcn_s_setprio(1);
        mfma16(0, af, bv);
        __builtin_amdgcn_s_setprio(0);

        readA4(A1, 4, af);
        asm volatile("s_waitcnt lgkmcnt(0)" ::: "memory");
        __builtin_amdgcn_s_setprio(1);
        mfma16(4, af, bv);
        __builtin_amdgcn_s_setprio(0);
    }

    // epilogue: C/D layout col=lane&15, row=quad*4+reg; leaky + store
#pragma unroll
    for (int im = 0; im < 8; ++im) {
#pragma unroll
        for (int in = 0; in < 4; ++in) {
#pragma unroll
            for (int reg = 0; reg < 4; ++reg) {
                int r = wm * 128 + im * 16 + fq * 4 + reg;
                int col = wn * 64 + in * 16 + fr;
                float v = acc[im][in][reg];
                if (act) v = v > 0.f ? v : 0.01f * v;
                size_t off = (tokbase + row0 + r) * fout + col0 + col;
                if (outb) outb[off] = f2bf(v);
                else      outf[off] = v;
            }
        }
    }
}

// ---------------------------------------------------------------------------
// Launch. Workspace: gw0T 64K | gw1T 8K | xz 16.8M | coef 0.5M | cpad 2M |
// actB 33.6M; then adaptive gb tier for wmT (+actA at gb=32).
// ---------------------------------------------------------------------------
extern "C" void kernel_launch(void* const* d_in, const int* in_sizes, int n_in,
                              void* d_out, int out_size, void* d_ws, size_t ws_size,
                              hipStream_t stream)
{
    const float* z = (const float*)d_in[0];
    const float* c = (const float*)d_in[1];
    const float* w[5]  = {(const float*)d_in[2], (const float*)d_in[4],
                          (const float*)d_in[6], (const float*)d_in[8],
                          (const float*)d_in[10]};
    const float* bs[5] = {(const float*)d_in[3], (const float*)d_in[5],
                          (const float*)d_in[7], (const float*)d_in[9],
                          (const float*)d_in[11]};
    const float* gw0 = (const float*)d_in[12]; const float* gb0 = (const float*)d_in[13];
    const float* gw1 = (const float*)d_in[14]; const float* gb1 = (const float*)d_in[15];
    const float* gw2 = (const float*)d_in[16]; const float* gb2 = (const float*)d_in[17];

    const size_t g0t_b  = (size_t)GATEH * INPUT_ * 2;   // 64 KB
    const size_t g1t_b  = (size_t)GATEH * GATEH * 2;    // 8 KB
    const size_t xz_b   = (size_t)NTOK * INPUT_ * 2;
    const size_t coef_b = (size_t)NTOK * E_ * 4;
    const size_t cpad_b = (size_t)NTOK * KTAIL * 2;
    const size_t act_b  = (size_t)NTOK * HIDDEN * 2;
    const size_t wmun   = (size_t)(INTER_ + KTAIL) * HIDDEN * 2;  // per-batch max

    char* p = (char*)d_ws;
    unsigned short* gw0T  = (unsigned short*)p;  p += g0t_b;
    unsigned short* gw1T  = (unsigned short*)p;  p += g1t_b;
    unsigned short* xzb   = (unsigned short*)p;  p += xz_b;
    float*          coef  = (float*)p;           p += coef_b;
    unsigned short* cpad  = (unsigned short*)p;  p += cpad_b;
    unsigned short* actB  = (unsigned short*)p;  p += act_b;

    size_t base = g0t_b + g1t_b + xz_b + coef_b + cpad_b + act_b;
    size_t avail = (ws_size > base) ? ws_size - base : 0;

    int gb;
    unsigned short* actA;
    unsigned short* wmT;
    if (avail >= act_b + 32 * wmun) {
        gb = 32; actA = (unsigned short*)p; p += act_b; wmT = (unsigned short*)p;
    } else {
        actA = (unsigned short*)d_out;
        wmT  = (unsigned short*)p;
        gb = 1;
        for (int g = 16; g >= 2; g >>= 1)
            if (avail >= (size_t)g * wmun) { gb = g; break; }
    }

    wprep_kernel<<<(GATEH * (INPUT_ + GATEH) + 255) / 256, 256, 0, stream>>>(
        gw0, gw1, gw0T, gw1T);
    gate_kernel<<<NTOK / 64, 256, 0, stream>>>(
        z, c, gb0, gb1, gw2, gb2, gw0T, gw1T, coef, cpad, xzb);

    struct L { int fin, fout, act; const unsigned short* in; unsigned short* outb; };
    L Ls[5] = {
        {INPUT_, HIDDEN, 1, actB /*unused*/, actA},
        {INTER_, HIDDEN, 1, actA, actB},
        {INTER_, HIDDEN, 1, actB, actA},
        {INTER_, HIDDEN, 1, actA, actB},
        {INTER_, OUTD,   0, actB, 0},
    };

    for (int Li = 0; Li < 5; ++Li) {
        int fin = Ls[Li].fin, fout = Ls[Li].fout;
        int nblk = (fin / MI) * (fout / MO);
        for (int g = 0; g < B_; g += gb) {
            mixT_kernel<<<nblk, 256, 0, stream>>>(
                w[Li], bs[Li], coef, wmT, fin, fout, gb, g);
            gemm_kernel<<<dim3(fout / 256, T_ / 256, gb), 512, 0, stream>>>(
                xzb, Ls[Li].in, wmT, cpad,
                (float*)d_out, Ls[Li].outb, fin + KTAIL, fout, Ls[Li].act, g);
        }
    }
}

// Round 3
// 658.102 us; speedup vs baseline: 1.0899x; 1.0410x over previous
//
#include <hip/hip_runtime.h>
#include <math.h>

// Problem constants
#define B_     32
#define T_     512
#define LATENT 64
#define COND   448
#define HIDDEN 1024
#define OUTD   512
#define E_     8
#define INPUT_ 512     // LATENT + COND
#define INTER_ 1536    // LATENT + COND + HIDDEN
#define GATEH  64
#define NTOK   (B_ * T_)   // 16384
#define KTAIL  64          // bias-mix folded into K as one extra 64-chunk (BK=64 aligned)

typedef __attribute__((ext_vector_type(8))) short short8;   // bf16x8 MFMA A/B frag
typedef __attribute__((ext_vector_type(4))) float f32x4;    // MFMA C/D frag

static __device__ __forceinline__ unsigned short f2bf(float x) {
    unsigned u = __float_as_uint(x);
    u += 0x7fffu + ((u >> 16) & 1u);
    return (unsigned short)(u >> 16);
}

// ---------------------------------------------------------------------------
// wprep: transpose gate weights to bf16 [n][k] rows for MFMA B-operands.
// ---------------------------------------------------------------------------
__global__ __launch_bounds__(256) void wprep_kernel(
    const float* __restrict__ gw0, const float* __restrict__ gw1,
    unsigned short* __restrict__ gw0T, unsigned short* __restrict__ gw1T)
{
    int idx = blockIdx.x * 256 + threadIdx.x;
    if (idx < GATEH * INPUT_) {
        int n = idx >> 9, k = idx & 511;
        gw0T[n * INPUT_ + k] = f2bf(gw0[k * GATEH + n]);
    } else {
        int i2 = idx - GATEH * INPUT_;
        if (i2 < GATEH * GATEH) {
            int n = i2 >> 6, k = i2 & 63;
            gw1T[n * GATEH + k] = f2bf(gw1[k * GATEH + n]);
        }
    }
}

// ---------------------------------------------------------------------------
// Gate (MFMA): 64 tokens/block, 256 threads (4 waves).
// ---------------------------------------------------------------------------
__global__ __launch_bounds__(256) void gate_kernel(
    const float* __restrict__ z, const float* __restrict__ c,
    const float* __restrict__ gb0,
    const float* __restrict__ gb1,
    const float* __restrict__ gw2, const float* __restrict__ gb2,
    const unsigned short* __restrict__ gw0T,
    const unsigned short* __restrict__ gw1T,
    float* __restrict__ coef, unsigned short* __restrict__ coefpad,
    unsigned short* __restrict__ xzb)
{
    __shared__ unsigned short Hb[GATEH][72];   // g0 out, bf16, pad->2-way free
    __shared__ float H2[GATEH][65];            // g1 out, fp32
    __shared__ float sLg[GATEH][E_];           // logits

    const int tid = threadIdx.x;
    const int lane = tid & 63;
    const int wv = tid >> 6;
    const int tok0 = blockIdx.x * 64;

    // ---- phase 0: z|c -> xz bf16 ----
#pragma unroll
    for (int i = 0; i < 4; ++i) {              // z: 64 tok x 64
        int idx = i * 256 + tid;
        int tr = idx >> 4, c4 = (idx & 15) * 4;
        float4 v = *(const float4*)(z + ((size_t)(tok0 + tr) * LATENT) + c4);
        ushort4 o = {f2bf(v.x), f2bf(v.y), f2bf(v.z), f2bf(v.w)};
        *(ushort4*)(xzb + (size_t)(tok0 + tr) * INPUT_ + c4) = o;
    }
#pragma unroll
    for (int i = 0; i < 28; ++i) {             // c: 64 tok x 448
        int idx = i * 256 + tid;
        int tr = idx / 112, c4 = (idx % 112) * 4;
        float4 v = *(const float4*)(c + ((size_t)(tok0 + tr) * COND) + c4);
        ushort4 o = {f2bf(v.x), f2bf(v.y), f2bf(v.z), f2bf(v.w)};
        *(ushort4*)(xzb + (size_t)(tok0 + tr) * INPUT_ + LATENT + c4) = o;
    }
    __threadfence_block();
    __syncthreads();

    const int fr = lane & 15, fq = lane >> 4;
    const int wm0 = (wv & 1) * 32, wn0 = (wv >> 1) * 32;

    // ---- g0 MFMA ----
    f32x4 acc[2][2];
#pragma unroll
    for (int im = 0; im < 2; ++im)
#pragma unroll
        for (int in = 0; in < 2; ++in) acc[im][in] = (f32x4){0.f,0.f,0.f,0.f};

    for (int k0 = 0; k0 < INPUT_; k0 += 32) {
        short8 af[2], bf[2];
#pragma unroll
        for (int im = 0; im < 2; ++im)
            af[im] = *(const short8*)(xzb + (size_t)(tok0 + wm0 + im*16 + fr) * INPUT_
                                          + k0 + fq * 8);
#pragma unroll
        for (int in = 0; in < 2; ++in)
            bf[in] = *(const short8*)(gw0T + (size_t)(wn0 + in*16 + fr) * INPUT_
                                           + k0 + fq * 8);
#pragma unroll
        for (int im = 0; im < 2; ++im)
#pragma unroll
            for (int in = 0; in < 2; ++in)
                acc[im][in] = __builtin_amdgcn_mfma_f32_16x16x32_bf16(
                    af[im], bf[in], acc[im][in], 0, 0, 0);
    }
    // C layout: col=lane&15, row=(lane>>4)*4+reg
#pragma unroll
    for (int im = 0; im < 2; ++im)
#pragma unroll
        for (int in = 0; in < 2; ++in)
#pragma unroll
            for (int reg = 0; reg < 4; ++reg) {
                int m = wm0 + im*16 + fq*4 + reg;
                int n = wn0 + in*16 + fr;
                float h = acc[im][in][reg] + gb0[n];
                h = h > 0.f ? h : 0.01f * h;
                Hb[m][n] = f2bf(h);
            }
    __syncthreads();

    // ---- g1 MFMA ----
    f32x4 a2[2][2];
#pragma unroll
    for (int im = 0; im < 2; ++im)
#pragma unroll
        for (int in = 0; in < 2; ++in) a2[im][in] = (f32x4){0.f,0.f,0.f,0.f};
#pragma unroll
    for (int k0 = 0; k0 < GATEH; k0 += 32) {
        short8 af[2], bf[2];
#pragma unroll
        for (int im = 0; im < 2; ++im)
            af[im] = *(const short8*)(&Hb[wm0 + im*16 + fr][k0 + fq*8]);
#pragma unroll
        for (int in = 0; in < 2; ++in)
            bf[in] = *(const short8*)(gw1T + (size_t)(wn0 + in*16 + fr) * GATEH
                                           + k0 + fq * 8);
#pragma unroll
        for (int im = 0; im < 2; ++im)
#pragma unroll
            for (int in = 0; in < 2; ++in)
                a2[im][in] = __builtin_amdgcn_mfma_f32_16x16x32_bf16(
                    af[im], bf[in], a2[im][in], 0, 0, 0);
    }
#pragma unroll
    for (int im = 0; im < 2; ++im)
#pragma unroll
        for (int in = 0; in < 2; ++in)
#pragma unroll
            for (int reg = 0; reg < 4; ++reg) {
                int m = wm0 + im*16 + fq*4 + reg;
                int n = wn0 + in*16 + fr;
                float h = a2[im][in][reg] + gb1[n];
                H2[m][n] = h > 0.f ? h : 0.01f * h;
            }
    __syncthreads();

    // ---- g2 (vector): thread -> (tok = tid>>2, 2 experts) ----
    {
        int tok = tid >> 2, e0 = (tid & 3) * 2;
        float l0 = gb2[e0], l1 = gb2[e0 + 1];
#pragma unroll
        for (int i = 0; i < GATEH; ++i) {
            float h = H2[tok][i];
            l0 = fmaf(h, gw2[i * E_ + e0], l0);
            l1 = fmaf(h, gw2[i * E_ + e0 + 1], l1);
        }
        sLg[tok][e0] = l0; sLg[tok][e0 + 1] = l1;
    }
    __syncthreads();

    // ---- softmax + outputs: one thread per token ----
    if (tid < 64) {
        int token = tok0 + tid;
        float lg[E_], m = -1e30f, s = 0.f;
#pragma unroll
        for (int e = 0; e < E_; ++e) { lg[e] = sLg[tid][e]; m = fmaxf(m, lg[e]); }
#pragma unroll
        for (int e = 0; e < E_; ++e) { lg[e] = expf(lg[e] - m); s += lg[e]; }
        float inv = 1.f / s;
        unsigned short pad[KTAIL];
#pragma unroll
        for (int e = 0; e < E_; ++e) {
            float cv = lg[e] * inv;
            coef[(size_t)token * E_ + e] = cv;
            pad[e] = f2bf(cv);
        }
#pragma unroll
        for (int j = E_; j < KTAIL; ++j) pad[j] = 0;
#pragma unroll
        for (int q = 0; q < KTAIL / 4; ++q)
            *(ushort4*)(coefpad + (size_t)token * KTAIL + q * 4) =
                *(const ushort4*)&pad[q * 4];
    }
}

// ---------------------------------------------------------------------------
// Transpose-mix v2: wmT[b][o][i] = bf16( sum_e coef0[b][e] * w[e][i][o] ).
// float4-vectorized staging; per-thread 8x8 sW slice cached in REGISTERS so
// the b-loop does zero LDS re-reads (was 32x re-read = 2 MB LDS/block).
// K-tail rows i in [fin, fin+8): bias[e][o]; [fin+8, fin+64): 0.
// ---------------------------------------------------------------------------
#define MI 32
#define MO 64
#define MP 65

__global__ __launch_bounds__(256) void mixT_kernel(
    const float* __restrict__ w,          // (E, fin, fout) fp32
    const float* __restrict__ bias,       // (E, fout) fp32
    const float* __restrict__ coef,       // (NTOK, 8)
    unsigned short* __restrict__ wmT,     // (gb, fout, fin+64) bf16
    int fin, int fout, int gb, int batch0)
{
    __shared__ float sW[E_][MI][MP];
    __shared__ float sC[B_][E_];
    const int t = threadIdx.x;
    const int fin_tot = fin + KTAIL;
    const int nbi = fin / MI;
    const int i0 = (blockIdx.x % nbi) * MI;
    const int o0 = (blockIdx.x / nbi) * MO;

    if (t < gb * E_)
        sC[t >> 3][t & 7] = coef[(size_t)(batch0 + (t >> 3)) * T_ * E_ + (t & 7)];

    // staging: 8 e x 32 i x 16 float4 = 4096 float4 / 256 thr = 16 iters
#pragma unroll
    for (int r = 0; r < 16; ++r) {
        int idx = r * 256 + t;
        int o4 = idx & 15;
        int i  = (idx >> 4) & 31;
        int e  = idx >> 9;
        float4 v = *(const float4*)(w + (size_t)e * fin * fout
                                      + (size_t)(i0 + i) * fout + o0 + o4 * 4);
        *(float4*)&sW[e][i][o4 * 4] = v;
    }
    __syncthreads();

    const int o  = t >> 2;
    const int i8 = (t & 3) * 8;

    // cache this thread's 8x8 slice in registers (2-way LDS reads = free)
    float rw[E_][8];
#pragma unroll
    for (int e = 0; e < E_; ++e)
#pragma unroll
        for (int j = 0; j < 8; ++j)
            rw[e][j] = sW[e][i8 + j][o];

    for (int b = 0; b < gb; ++b) {
        float v[8];
#pragma unroll
        for (int j = 0; j < 8; ++j) v[j] = 0.f;
#pragma unroll
        for (int e = 0; e < E_; ++e) {
            float cc = sC[b][e];
#pragma unroll
            for (int j = 0; j < 8; ++j)
                v[j] = fmaf(cc, rw[e][j], v[j]);
        }
        unsigned short u[8];
#pragma unroll
        for (int j = 0; j < 8; ++j) u[j] = f2bf(v[j]);
        *(int4*)(wmT + ((size_t)b * fout + o0 + o) * fin_tot + i0 + i8) = *(const int4*)u;
    }

    if (i0 == 0) {
        const int jj = t & 3;
        unsigned short u[8];
#pragma unroll
        for (int q = 0; q < 8; ++q)
            u[q] = (jj == 0) ? f2bf(bias[(size_t)q * fout + o0 + o]) : 0;
        unsigned short z8[8] = {0, 0, 0, 0, 0, 0, 0, 0};
        for (int b = 0; b < gb; ++b) {
            size_t rb = ((size_t)b * fout + o0 + o) * fin_tot + fin;
            *(int4*)(wmT + rb + jj * 8)      = *(const int4*)u;
            *(int4*)(wmT + rb + 32 + jj * 8) = *(const int4*)z8;
        }
    }
}

// ---------------------------------------------------------------------------
// MFMA GEMM, v4: 8-phase schedule + one-phase ds_read READ-AHEAD with counted
// lgkmcnt (never 0 in main loop) so the LDS drain overlaps the MFMA cluster.
// No "memory" clobbers on waitcnt asm (avoids compiler pre-drains); ordering
// via adjacent s_barrier + sched_barrier(0) pins (rule #18).
// 256x256 tile, BK=64, 512 thr (8 waves 2Mx4N, per-wave 128x64 = 8x4 frags).
// Double-buffered LDS 128 KiB. vmcnt(4) only at phases 1/3. Batch-clustered
// bijective XCD remap. XOR-swizzled staging (conflict-free, verified 0).
// ---------------------------------------------------------------------------
__global__ __launch_bounds__(512, 2) void gemm_kernel(
    const unsigned short* __restrict__ xz,      // (NTOK, 512) bf16
    const unsigned short* __restrict__ prev,    // (NTOK, 1024) bf16
    const unsigned short* __restrict__ wmT,     // (gb, fout, fin_tot) bf16
    const unsigned short* __restrict__ coefpad, // (NTOK, 64) bf16
    float* __restrict__ outf,                   // fp32 out (layer 4)
    unsigned short* __restrict__ outb,          // bf16 out (layers 0-3), or null
    int fin_tot, int fout, int act, int batch0)
{
    __shared__ __align__(16) unsigned short As[2][2][8192];   // 64 KiB
    __shared__ __align__(16) unsigned short Bs[2][2][8192];   // 64 KiB

    const int tid = threadIdx.x;
    const int lane = tid & 63;
    const int w8 = tid >> 6;          // wave 0..7
    const int wm = w8 & 1;            // M half
    const int wn = w8 >> 1;           // N quarter

    // ---- batch-clustered XCD remap (bijective when 8 | nwg) ----
    const int nx = gridDim.x;         // fout/256
    int bx = blockIdx.x, by = blockIdx.y, bz = blockIdx.z;
    {
        int nwg = nx * 2 * gridDim.z;
        if ((nwg & 7) == 0) {
            int f = blockIdx.x + nx * (blockIdx.y + 2 * blockIdx.z);
            int q = nwg >> 3;
            int wk = (f & 7) * q + (f >> 3);   // XCD (f&7) owns contiguous chunk
            int bpb = nx * 2;                  // blocks per batch
            bz = wk / bpb;
            int r = wk - bz * bpb;
            by = r / nx;
            bx = r - by * nx;
        }
    }

    const int row0 = by * 256;
    const int col0 = bx * 256;
    const size_t tokbase = (size_t)(batch0 + bz) * T_;
    const unsigned short* wmb = wmT + (size_t)bz * fin_tot * fout;

    // staging lane geometry (matches global_load_lds linear lane scatter)
    const int lrow = lane >> 2;                               // row in 16-row chunk
    const int lk8  = (((lane & 3) ^ ((lane >> 3) & 3)) * 8);  // swizzled k offset
    // frag-read geometry
    const int fr = lane & 15, fq = lane >> 4;
    const int koff = (fq ^ ((fr >> 1) & 3)) * 8;              // swizzled read offset
    const int roff = fr * 32 + koff;
    const int ktail0 = fin_tot - KTAIL;
    const int nt = fin_tot >> 6;                              // 9 or 25 K-tiles

    f32x4 acc[8][4];
#pragma unroll
    for (int im = 0; im < 8; ++im)
#pragma unroll
        for (int in = 0; in < 4; ++in)
            acc[im][in] = (f32x4){0.f, 0.f, 0.f, 0.f};

    // stage one A/B half-tile (256 rows x 32 k, 16 KB) of K-tile t, half kk
    auto stageA = [&](int t, int kk) {
        int k32 = (t << 6) + (kk << 5);
        const unsigned short* abase; int astr, acol;
        if (k32 < INPUT_)      { abase = xz;      astr = INPUT_; acol = k32; }
        else if (k32 < ktail0) { abase = prev;    astr = HIDDEN; acol = k32 - INPUT_; }
        else                   { abase = coefpad; astr = KTAIL;  acol = k32 - ktail0; }
        unsigned short* Ab = &As[t & 1][kk][0];
#pragma unroll
        for (int j = 0; j < 2; ++j) {
            int ch = w8 + 8 * j;              // chunk 0..15 (wave-uniform)
            const unsigned short* src = abase
                + (tokbase + row0 + ch * 16 + lrow) * (size_t)astr + acol + lk8;
            __builtin_amdgcn_global_load_lds(
                (const __attribute__((address_space(1))) unsigned int*)(const void*)src,
                (__attribute__((address_space(3))) unsigned int*)(void*)(Ab + ch * 512),
                16, 0, 0);
        }
    };
    auto stageB = [&](int t, int kk) {
        int k32 = (t << 6) + (kk << 5);
        unsigned short* Bb = &Bs[t & 1][kk][0];
#pragma unroll
        for (int j = 0; j < 2; ++j) {
            int ch = w8 + 8 * j;
            const unsigned short* src = wmb
                + (size_t)(col0 + ch * 16 + lrow) * fin_tot + k32 + lk8;
            __builtin_amdgcn_global_load_lds(
                (const __attribute__((address_space(1))) unsigned int*)(const void*)src,
                (__attribute__((address_space(3))) unsigned int*)(void*)(Bb + ch * 512),
                16, 0, 0);
        }
    };

    auto readA = [&](const unsigned short* Ak, int im0, short8* d4) {
#pragma unroll
        for (int q = 0; q < 4; ++q)
            d4[q] = *(const short8*)(Ak + (im0 + q) * 512 + roff);
    };
    auto readB = [&](const unsigned short* Bk, short8* d4) {
#pragma unroll
        for (int q = 0; q < 4; ++q)
            d4[q] = *(const short8*)(Bk + q * 512 + roff);
    };
    auto mfma16 = [&](int im0, short8* af, short8* bv) {
#pragma unroll
        for (int q = 0; q < 4; ++q)
#pragma unroll
            for (int in = 0; in < 4; ++in)
                acc[im0 + q][in] = __builtin_amdgcn_mfma_f32_16x16x32_bf16(
                    af[q], bv[in], acc[im0 + q][in], 0, 0, 0);
    };

    short8 afX[4], afY[4], bvA[4], bvB[4];

    // ---- prologue: stage tile 0; pre-read phase-0 operands ----
    stageA(0, 0); stageB(0, 0); stageA(0, 1); stageB(0, 1);
    asm volatile("s_waitcnt vmcnt(4)");
    __builtin_amdgcn_s_barrier();
    readA(&As[0][0][wm * 4096], 0, afX);
    readB(&Bs[0][0][wn * 2048], bvA);

    // ---- main loop: 4 phases per K-tile, read-ahead by one phase ----
    for (int t = 0; t < nt - 1; ++t) {
        const int cur = t & 1, nxt = cur ^ 1;
        const unsigned short* A0  = &As[cur][0][wm * 4096];
        const unsigned short* A1  = &As[cur][1][wm * 4096];
        const unsigned short* B1p = &Bs[cur][1][wn * 2048];
        const unsigned short* A0n = &As[nxt][0][wm * 4096];
        const unsigned short* B0n = &Bs[nxt][0][wn * 2048];

        // phase 0: mfma(im0-3, kk0); read-ahead A kk0 hi
        stageA(t + 1, 0);
        readA(A0, 4, afY);
        __builtin_amdgcn_s_barrier();
        __builtin_amdgcn_sched_barrier(0);
        asm volatile("s_waitcnt lgkmcnt(4)");
        __builtin_amdgcn_sched_barrier(0);
        __builtin_amdgcn_s_setprio(1);
        mfma16(0, afX, bvA);
        __builtin_amdgcn_s_setprio(0);
        __builtin_amdgcn_s_barrier();

        // phase 1: mfma(im4-7, kk0); read-ahead A kk1 lo + B kk1
        stageB(t + 1, 0);
        asm volatile("s_waitcnt vmcnt(4)");
        __builtin_amdgcn_s_barrier();
        readA(A1, 0, afX);
        readB(B1p, bvB);
        __builtin_amdgcn_sched_barrier(0);
        asm volatile("s_waitcnt lgkmcnt(8)");
        __builtin_amdgcn_sched_barrier(0);
        __builtin_amdgcn_s_setprio(1);
        mfma16(4, afY, bvA);
        __builtin_amdgcn_s_setprio(0);
        __builtin_amdgcn_s_barrier();

        // phase 2: mfma(im0-3, kk1); read-ahead A kk1 hi
        stageA(t + 1, 1);
        readA(A1, 4, afY);
        __builtin_amdgcn_s_barrier();
        __builtin_amdgcn_sched_barrier(0);
        asm volatile("s_waitcnt lgkmcnt(4)");
        __builtin_amdgcn_sched_barrier(0);
        __builtin_amdgcn_s_setprio(1);
        mfma16(0, afX, bvB);
        __builtin_amdgcn_s_setprio(0);
        __builtin_amdgcn_s_barrier();

        // phase 3: mfma(im4-7, kk1); read-ahead next tile kk0 lo + B
        stageB(t + 1, 1);
        asm volatile("s_waitcnt vmcnt(4)");
        __builtin_amdgcn_s_barrier();
        readA(A0n, 0, afX);
        readB(B0n, bvA);
        __builtin_amdgcn_sched_barrier(0);
        asm volatile("s_waitcnt lgkmcnt(8)");
        __builtin_amdgcn_sched_barrier(0);
        __builtin_amdgcn_s_setprio(1);
        mfma16(4, afY, bvB);
        __builtin_amdgcn_s_setprio(0);
        __builtin_amdgcn_s_barrier();
    }

    // ---- final tile: no staging ----
    {
        const int cur = (nt - 1) & 1;
        const unsigned short* A0  = &As[cur][0][wm * 4096];
        const unsigned short* A1  = &As[cur][1][wm * 4096];
        const unsigned short* B1p = &Bs[cur][1][wn * 2048];

        readA(A0, 4, afY);
        __builtin_amdgcn_sched_barrier(0);
        asm volatile("s_waitcnt lgkmcnt(4)");
        __builtin_amdgcn_sched_barrier(0);
        __builtin_amdgcn_s_setprio(1);
        mfma16(0, afX, bvA);
        __builtin_amdgcn_s_setprio(0);

        asm volatile("s_waitcnt vmcnt(0)");   // kk1 halves of final tile landed
        __builtin_amdgcn_s_barrier();

        readA(A1, 0, afX);
        readB(B1p, bvB);
        __builtin_amdgcn_sched_barrier(0);
        asm volatile("s_waitcnt lgkmcnt(8)");
        __builtin_amdgcn_sched_barrier(0);
        __builtin_amdgcn_s_setprio(1);
        mfma16(4, afY, bvA);
        __builtin_amdgcn_s_setprio(0);

        readA(A1, 4, afY);
        __builtin_amdgcn_sched_barrier(0);
        asm volatile("s_waitcnt lgkmcnt(4)");
        __builtin_amdgcn_sched_barrier(0);
        __builtin_amdgcn_s_setprio(1);
        mfma16(0, afX, bvB);
        __builtin_amdgcn_s_setprio(0);

        __builtin_amdgcn_sched_barrier(0);
        asm volatile("s_waitcnt lgkmcnt(0)");
        __builtin_amdgcn_sched_barrier(0);
        __builtin_amdgcn_s_setprio(1);
        mfma16(4, afY, bvB);
        __builtin_amdgcn_s_setprio(0);
    }

    // epilogue: C/D layout col=lane&15, row=quad*4+reg; leaky + store
#pragma unroll
    for (int im = 0; im < 8; ++im) {
#pragma unroll
        for (int in = 0; in < 4; ++in) {
#pragma unroll
            for (int reg = 0; reg < 4; ++reg) {
                int r = wm * 128 + im * 16 + fq * 4 + reg;
                int col = wn * 64 + in * 16 + fr;
                float v = acc[im][in][reg];
                if (act) v = v > 0.f ? v : 0.01f * v;
                size_t off = (tokbase + row0 + r) * fout + col0 + col;
                if (outb) outb[off] = f2bf(v);
                else      outf[off] = v;
            }
        }
    }
}

// ---------------------------------------------------------------------------
// Launch. Workspace: gw0T 64K | gw1T 8K | xz 16.8M | coef 0.5M | cpad 2M |
// actB 33.6M; then adaptive gb tier for wmT (+actA at gb=32).
// ---------------------------------------------------------------------------
extern "C" void kernel_launch(void* const* d_in, const int* in_sizes, int n_in,
                              void* d_out, int out_size, void* d_ws, size_t ws_size,
                              hipStream_t stream)
{
    const float* z = (const float*)d_in[0];
    const float* c = (const float*)d_in[1];
    const float* w[5]  = {(const float*)d_in[2], (const float*)d_in[4],
                          (const float*)d_in[6], (const float*)d_in[8],
                          (const float*)d_in[10]};
    const float* bs[5] = {(const float*)d_in[3], (const float*)d_in[5],
                          (const float*)d_in[7], (const float*)d_in[9],
                          (const float*)d_in[11]};
    const float* gw0 = (const float*)d_in[12]; const float* gb0 = (const float*)d_in[13];
    const float* gw1 = (const float*)d_in[14]; const float* gb1 = (const float*)d_in[15];
    const float* gw2 = (const float*)d_in[16]; const float* gb2 = (const float*)d_in[17];

    const size_t g0t_b  = (size_t)GATEH * INPUT_ * 2;   // 64 KB
    const size_t g1t_b  = (size_t)GATEH * GATEH * 2;    // 8 KB
    const size_t xz_b   = (size_t)NTOK * INPUT_ * 2;
    const size_t coef_b = (size_t)NTOK * E_ * 4;
    const size_t cpad_b = (size_t)NTOK * KTAIL * 2;
    const size_t act_b  = (size_t)NTOK * HIDDEN * 2;
    const size_t wmun   = (size_t)(INTER_ + KTAIL) * HIDDEN * 2;  // per-batch max

    char* p = (char*)d_ws;
    unsigned short* gw0T  = (unsigned short*)p;  p += g0t_b;
    unsigned short* gw1T  = (unsigned short*)p;  p += g1t_b;
    unsigned short* xzb   = (unsigned short*)p;  p += xz_b;
    float*          coef  = (float*)p;           p += coef_b;
    unsigned short* cpad  = (unsigned short*)p;  p += cpad_b;
    unsigned short* actB  = (unsigned short*)p;  p += act_b;

    size_t base = g0t_b + g1t_b + xz_b + coef_b + cpad_b + act_b;
    size_t avail = (ws_size > base) ? ws_size - base : 0;

    int gb;
    unsigned short* actA;
    unsigned short* wmT;
    if (avail >= act_b + 32 * wmun) {
        gb = 32; actA = (unsigned short*)p; p += act_b; wmT = (unsigned short*)p;
    } else {
        actA = (unsigned short*)d_out;
        wmT  = (unsigned short*)p;
        gb = 1;
        for (int g = 16; g >= 2; g >>= 1)
            if (avail >= (size_t)g * wmun) { gb = g; break; }
    }

    wprep_kernel<<<(GATEH * (INPUT_ + GATEH) + 255) / 256, 256, 0, stream>>>(
        gw0, gw1, gw0T, gw1T);
    gate_kernel<<<NTOK / 64, 256, 0, stream>>>(
        z, c, gb0, gb1, gw2, gb2, gw0T, gw1T, coef, cpad, xzb);

    struct L { int fin, fout, act; const unsigned short* in; unsigned short* outb; };
    L Ls[5] = {
        {INPUT_, HIDDEN, 1, actB /*unused*/, actA},
        {INTER_, HIDDEN, 1, actA, actB},
        {INTER_, HIDDEN, 1, actB, actA},
        {INTER_, HIDDEN, 1, actA, actB},
        {INTER_, OUTD,   0, actB, 0},
    };

    for (int Li = 0; Li < 5; ++Li) {
        int fin = Ls[Li].fin, fout = Ls[Li].fout;
        int nblk = (fin / MI) * (fout / MO);
        for (int g = 0; g < B_; g += gb) {
            mixT_kernel<<<nblk, 256, 0, stream>>>(
                w[Li], bs[Li], coef, wmT, fin, fout, gb, g);
            gemm_kernel<<<dim3(fout / 256, T_ / 256, gb), 512, 0, stream>>>(
                xzb, Ls[Li].in, wmT, cpad,
                (float*)d_out, Ls[Li].outb, fin + KTAIL, fout, Ls[Li].act, g);
        }
    }
}

// Round 4
// 609.378 us; speedup vs baseline: 1.1770x; 1.0800x over previous
//
#include <hip/hip_runtime.h>
#include <math.h>

// Problem constants
#define B_     32
#define T_     512
#define LATENT 64
#define COND   448
#define HIDDEN 1024
#define OUTD   512
#define E_     8
#define INPUT_ 512     // LATENT + COND
#define INTER_ 1536    // LATENT + COND + HIDDEN
#define GATEH  64
#define NTOK   (B_ * T_)   // 16384
#define KTAIL  64          // bias-mix folded into K as one extra 64-chunk (BK=64 aligned)

typedef __attribute__((ext_vector_type(8))) short short8;   // bf16x8 MFMA A/B frag
typedef __attribute__((ext_vector_type(4))) float f32x4;    // MFMA C/D frag

typedef __attribute__((address_space(3))) const unsigned short* lds_cptr;

static __device__ __forceinline__ unsigned short f2bf(float x) {
    unsigned u = __float_as_uint(x);
    u += 0x7fffu + ((u >> 16) & 1u);
    return (unsigned short)(u >> 16);
}

// 4x ds_read_b128 at offsets 0/1024/2048/3072 from p, as ONE inline-asm unit.
// Opaque to the compiler's waitcnt pass: no auto-inserted vmcnt/lgkm drains.
// lgkm accounting is owned by the caller (counted s_waitcnt + sched_barrier).
static __device__ __forceinline__ void dsr4(const unsigned short* p, short8* d) {
    lds_cptr q = (lds_cptr)p;
    asm volatile("ds_read_b128 %0, %4 offset:0\n\t"
                 "ds_read_b128 %1, %4 offset:1024\n\t"
                 "ds_read_b128 %2, %4 offset:2048\n\t"
                 "ds_read_b128 %3, %4 offset:3072"
                 : "=&v"(d[0]), "=&v"(d[1]), "=&v"(d[2]), "=&v"(d[3])
                 : "v"(q));
}

// ---------------------------------------------------------------------------
// wprep: transpose gate weights to bf16 [n][k] rows for MFMA B-operands.
// ---------------------------------------------------------------------------
__global__ __launch_bounds__(256) void wprep_kernel(
    const float* __restrict__ gw0, const float* __restrict__ gw1,
    unsigned short* __restrict__ gw0T, unsigned short* __restrict__ gw1T)
{
    int idx = blockIdx.x * 256 + threadIdx.x;
    if (idx < GATEH * INPUT_) {
        int n = idx >> 9, k = idx & 511;
        gw0T[n * INPUT_ + k] = f2bf(gw0[k * GATEH + n]);
    } else {
        int i2 = idx - GATEH * INPUT_;
        if (i2 < GATEH * GATEH) {
            int n = i2 >> 6, k = i2 & 63;
            gw1T[n * GATEH + k] = f2bf(gw1[k * GATEH + n]);
        }
    }
}

// ---------------------------------------------------------------------------
// Gate (MFMA): 64 tokens/block, 256 threads (4 waves).
// ---------------------------------------------------------------------------
__global__ __launch_bounds__(256) void gate_kernel(
    const float* __restrict__ z, const float* __restrict__ c,
    const float* __restrict__ gb0,
    const float* __restrict__ gb1,
    const float* __restrict__ gw2, const float* __restrict__ gb2,
    const unsigned short* __restrict__ gw0T,
    const unsigned short* __restrict__ gw1T,
    float* __restrict__ coef, unsigned short* __restrict__ coefpad,
    unsigned short* __restrict__ xzb)
{
    __shared__ unsigned short Hb[GATEH][72];   // g0 out, bf16, pad->2-way free
    __shared__ float H2[GATEH][65];            // g1 out, fp32
    __shared__ float sLg[GATEH][E_];           // logits

    const int tid = threadIdx.x;
    const int lane = tid & 63;
    const int wv = tid >> 6;
    const int tok0 = blockIdx.x * 64;

    // ---- phase 0: z|c -> xz bf16 ----
#pragma unroll
    for (int i = 0; i < 4; ++i) {              // z: 64 tok x 64
        int idx = i * 256 + tid;
        int tr = idx >> 4, c4 = (idx & 15) * 4;
        float4 v = *(const float4*)(z + ((size_t)(tok0 + tr) * LATENT) + c4);
        ushort4 o = {f2bf(v.x), f2bf(v.y), f2bf(v.z), f2bf(v.w)};
        *(ushort4*)(xzb + (size_t)(tok0 + tr) * INPUT_ + c4) = o;
    }
#pragma unroll
    for (int i = 0; i < 28; ++i) {             // c: 64 tok x 448
        int idx = i * 256 + tid;
        int tr = idx / 112, c4 = (idx % 112) * 4;
        float4 v = *(const float4*)(c + ((size_t)(tok0 + tr) * COND) + c4);
        ushort4 o = {f2bf(v.x), f2bf(v.y), f2bf(v.z), f2bf(v.w)};
        *(ushort4*)(xzb + (size_t)(tok0 + tr) * INPUT_ + LATENT + c4) = o;
    }
    __threadfence_block();
    __syncthreads();

    const int fr = lane & 15, fq = lane >> 4;
    const int wm0 = (wv & 1) * 32, wn0 = (wv >> 1) * 32;

    // ---- g0 MFMA ----
    f32x4 acc[2][2];
#pragma unroll
    for (int im = 0; im < 2; ++im)
#pragma unroll
        for (int in = 0; in < 2; ++in) acc[im][in] = (f32x4){0.f,0.f,0.f,0.f};

    for (int k0 = 0; k0 < INPUT_; k0 += 32) {
        short8 af[2], bf[2];
#pragma unroll
        for (int im = 0; im < 2; ++im)
            af[im] = *(const short8*)(xzb + (size_t)(tok0 + wm0 + im*16 + fr) * INPUT_
                                          + k0 + fq * 8);
#pragma unroll
        for (int in = 0; in < 2; ++in)
            bf[in] = *(const short8*)(gw0T + (size_t)(wn0 + in*16 + fr) * INPUT_
                                           + k0 + fq * 8);
#pragma unroll
        for (int im = 0; im < 2; ++im)
#pragma unroll
            for (int in = 0; in < 2; ++in)
                acc[im][in] = __builtin_amdgcn_mfma_f32_16x16x32_bf16(
                    af[im], bf[in], acc[im][in], 0, 0, 0);
    }
    // C layout: col=lane&15, row=(lane>>4)*4+reg
#pragma unroll
    for (int im = 0; im < 2; ++im)
#pragma unroll
        for (int in = 0; in < 2; ++in)
#pragma unroll
            for (int reg = 0; reg < 4; ++reg) {
                int m = wm0 + im*16 + fq*4 + reg;
                int n = wn0 + in*16 + fr;
                float h = acc[im][in][reg] + gb0[n];
                h = h > 0.f ? h : 0.01f * h;
                Hb[m][n] = f2bf(h);
            }
    __syncthreads();

    // ---- g1 MFMA ----
    f32x4 a2[2][2];
#pragma unroll
    for (int im = 0; im < 2; ++im)
#pragma unroll
        for (int in = 0; in < 2; ++in) a2[im][in] = (f32x4){0.f,0.f,0.f,0.f};
#pragma unroll
    for (int k0 = 0; k0 < GATEH; k0 += 32) {
        short8 af[2], bf[2];
#pragma unroll
        for (int im = 0; im < 2; ++im)
            af[im] = *(const short8*)(&Hb[wm0 + im*16 + fr][k0 + fq*8]);
#pragma unroll
        for (int in = 0; in < 2; ++in)
            bf[in] = *(const short8*)(gw1T + (size_t)(wn0 + in*16 + fr) * GATEH
                                           + k0 + fq * 8);
#pragma unroll
        for (int im = 0; im < 2; ++im)
#pragma unroll
            for (int in = 0; in < 2; ++in)
                a2[im][in] = __builtin_amdgcn_mfma_f32_16x16x32_bf16(
                    af[im], bf[in], a2[im][in], 0, 0, 0);
    }
#pragma unroll
    for (int im = 0; im < 2; ++im)
#pragma unroll
        for (int in = 0; in < 2; ++in)
#pragma unroll
            for (int reg = 0; reg < 4; ++reg) {
                int m = wm0 + im*16 + fq*4 + reg;
                int n = wn0 + in*16 + fr;
                float h = a2[im][in][reg] + gb1[n];
                H2[m][n] = h > 0.f ? h : 0.01f * h;
            }
    __syncthreads();

    // ---- g2 (vector): thread -> (tok = tid>>2, 2 experts) ----
    {
        int tok = tid >> 2, e0 = (tid & 3) * 2;
        float l0 = gb2[e0], l1 = gb2[e0 + 1];
#pragma unroll
        for (int i = 0; i < GATEH; ++i) {
            float h = H2[tok][i];
            l0 = fmaf(h, gw2[i * E_ + e0], l0);
            l1 = fmaf(h, gw2[i * E_ + e0 + 1], l1);
        }
        sLg[tok][e0] = l0; sLg[tok][e0 + 1] = l1;
    }
    __syncthreads();

    // ---- softmax + outputs: one thread per token ----
    if (tid < 64) {
        int token = tok0 + tid;
        float lg[E_], m = -1e30f, s = 0.f;
#pragma unroll
        for (int e = 0; e < E_; ++e) { lg[e] = sLg[tid][e]; m = fmaxf(m, lg[e]); }
#pragma unroll
        for (int e = 0; e < E_; ++e) { lg[e] = expf(lg[e] - m); s += lg[e]; }
        float inv = 1.f / s;
        unsigned short pad[KTAIL];
#pragma unroll
        for (int e = 0; e < E_; ++e) {
            float cv = lg[e] * inv;
            coef[(size_t)token * E_ + e] = cv;
            pad[e] = f2bf(cv);
        }
#pragma unroll
        for (int j = E_; j < KTAIL; ++j) pad[j] = 0;
#pragma unroll
        for (int q = 0; q < KTAIL / 4; ++q)
            *(ushort4*)(coefpad + (size_t)token * KTAIL + q * 4) =
                *(const ushort4*)&pad[q * 4];
    }
}

// ---------------------------------------------------------------------------
// Transpose-mix v2: wmT[b][o][i] = bf16( sum_e coef0[b][e] * w[e][i][o] ).
// float4-vectorized staging; per-thread 8x8 sW slice cached in REGISTERS.
// K-tail rows i in [fin, fin+8): bias[e][o]; [fin+8, fin+64): 0.
// ---------------------------------------------------------------------------
#define MI 32
#define MO 64
#define MP 65

__global__ __launch_bounds__(256) void mixT_kernel(
    const float* __restrict__ w,          // (E, fin, fout) fp32
    const float* __restrict__ bias,       // (E, fout) fp32
    const float* __restrict__ coef,       // (NTOK, 8)
    unsigned short* __restrict__ wmT,     // (gb, fout, fin+64) bf16
    int fin, int fout, int gb, int batch0)
{
    __shared__ float sW[E_][MI][MP];
    __shared__ float sC[B_][E_];
    const int t = threadIdx.x;
    const int fin_tot = fin + KTAIL;
    const int nbi = fin / MI;
    const int i0 = (blockIdx.x % nbi) * MI;
    const int o0 = (blockIdx.x / nbi) * MO;

    if (t < gb * E_)
        sC[t >> 3][t & 7] = coef[(size_t)(batch0 + (t >> 3)) * T_ * E_ + (t & 7)];

    // staging: 8 e x 32 i x 16 float4 = 4096 float4 / 256 thr = 16 iters
#pragma unroll
    for (int r = 0; r < 16; ++r) {
        int idx = r * 256 + t;
        int o4 = idx & 15;
        int i  = (idx >> 4) & 31;
        int e  = idx >> 9;
        float4 v = *(const float4*)(w + (size_t)e * fin * fout
                                      + (size_t)(i0 + i) * fout + o0 + o4 * 4);
        *(float4*)&sW[e][i][o4 * 4] = v;
    }
    __syncthreads();

    const int o  = t >> 2;
    const int i8 = (t & 3) * 8;

    // cache this thread's 8x8 slice in registers (2-way LDS reads = free)
    float rw[E_][8];
#pragma unroll
    for (int e = 0; e < E_; ++e)
#pragma unroll
        for (int j = 0; j < 8; ++j)
            rw[e][j] = sW[e][i8 + j][o];

    for (int b = 0; b < gb; ++b) {
        float v[8];
#pragma unroll
        for (int j = 0; j < 8; ++j) v[j] = 0.f;
#pragma unroll
        for (int e = 0; e < E_; ++e) {
            float cc = sC[b][e];
#pragma unroll
            for (int j = 0; j < 8; ++j)
                v[j] = fmaf(cc, rw[e][j], v[j]);
        }
        unsigned short u[8];
#pragma unroll
        for (int j = 0; j < 8; ++j) u[j] = f2bf(v[j]);
        *(int4*)(wmT + ((size_t)b * fout + o0 + o) * fin_tot + i0 + i8) = *(const int4*)u;
    }

    if (i0 == 0) {
        const int jj = t & 3;
        unsigned short u[8];
#pragma unroll
        for (int q = 0; q < 8; ++q)
            u[q] = (jj == 0) ? f2bf(bias[(size_t)q * fout + o0 + o]) : 0;
        unsigned short z8[8] = {0, 0, 0, 0, 0, 0, 0, 0};
        for (int b = 0; b < gb; ++b) {
            size_t rb = ((size_t)b * fout + o0 + o) * fin_tot + fin;
            *(int4*)(wmT + rb + jj * 8)      = *(const int4*)u;
            *(int4*)(wmT + rb + 32 + jj * 8) = *(const int4*)z8;
        }
    }
}

// ---------------------------------------------------------------------------
// MFMA GEMM, v5: identical schedule to v4 (8-phase, read-ahead, counted
// vmcnt(4)/lgkmcnt(4|8), never 0 in main loop) BUT fragment reads are
// inline-asm ds_read_b128 -- opaque to the compiler's waitcnt pass, so it
// cannot insert its own vmcnt(0) drains before them (the v2-v4 plateau at
// ~740 TF == the documented drain0 plateau). All lgkm/vm counting is owned
// here; sched_barrier(0) pins per rule #18.
// ---------------------------------------------------------------------------
__global__ __launch_bounds__(512, 2) void gemm_kernel(
    const unsigned short* __restrict__ xz,      // (NTOK, 512) bf16
    const unsigned short* __restrict__ prev,    // (NTOK, 1024) bf16
    const unsigned short* __restrict__ wmT,     // (gb, fout, fin_tot) bf16
    const unsigned short* __restrict__ coefpad, // (NTOK, 64) bf16
    float* __restrict__ outf,                   // fp32 out (layer 4)
    unsigned short* __restrict__ outb,          // bf16 out (layers 0-3), or null
    int fin_tot, int fout, int act, int batch0)
{
    __shared__ __align__(16) unsigned short As[2][2][8192];   // 64 KiB
    __shared__ __align__(16) unsigned short Bs[2][2][8192];   // 64 KiB

    const int tid = threadIdx.x;
    const int lane = tid & 63;
    const int w8 = tid >> 6;          // wave 0..7
    const int wm = w8 & 1;            // M half
    const int wn = w8 >> 1;           // N quarter

    // ---- batch-clustered XCD remap (bijective when 8 | nwg) ----
    const int nx = gridDim.x;         // fout/256
    int bx = blockIdx.x, by = blockIdx.y, bz = blockIdx.z;
    {
        int nwg = nx * 2 * gridDim.z;
        if ((nwg & 7) == 0) {
            int f = blockIdx.x + nx * (blockIdx.y + 2 * blockIdx.z);
            int q = nwg >> 3;
            int wk = (f & 7) * q + (f >> 3);   // XCD (f&7) owns contiguous chunk
            int bpb = nx * 2;                  // blocks per batch
            bz = wk / bpb;
            int r = wk - bz * bpb;
            by = r / nx;
            bx = r - by * nx;
        }
    }

    const int row0 = by * 256;
    const int col0 = bx * 256;
    const size_t tokbase = (size_t)(batch0 + bz) * T_;
    const unsigned short* wmb = wmT + (size_t)bz * fin_tot * fout;

    // staging lane geometry (matches global_load_lds linear lane scatter)
    const int lrow = lane >> 2;                               // row in 16-row chunk
    const int lk8  = (((lane & 3) ^ ((lane >> 3) & 3)) * 8);  // swizzled k offset
    // frag-read geometry
    const int fr = lane & 15, fq = lane >> 4;
    const int koff = (fq ^ ((fr >> 1) & 3)) * 8;              // swizzled read offset
    const int roff = fr * 32 + koff;
    const int ktail0 = fin_tot - KTAIL;
    const int nt = fin_tot >> 6;                              // 9 or 25 K-tiles

    f32x4 acc[8][4];
#pragma unroll
    for (int im = 0; im < 8; ++im)
#pragma unroll
        for (int in = 0; in < 4; ++in)
            acc[im][in] = (f32x4){0.f, 0.f, 0.f, 0.f};

    // stage one A/B half-tile (256 rows x 32 k, 16 KB) of K-tile t, half kk
    auto stageA = [&](int t, int kk) {
        int k32 = (t << 6) + (kk << 5);
        const unsigned short* abase; int astr, acol;
        if (k32 < INPUT_)      { abase = xz;      astr = INPUT_; acol = k32; }
        else if (k32 < ktail0) { abase = prev;    astr = HIDDEN; acol = k32 - INPUT_; }
        else                   { abase = coefpad; astr = KTAIL;  acol = k32 - ktail0; }
        unsigned short* Ab = &As[t & 1][kk][0];
#pragma unroll
        for (int j = 0; j < 2; ++j) {
            int ch = w8 + 8 * j;              // chunk 0..15 (wave-uniform)
            const unsigned short* src = abase
                + (tokbase + row0 + ch * 16 + lrow) * (size_t)astr + acol + lk8;
            __builtin_amdgcn_global_load_lds(
                (const __attribute__((address_space(1))) unsigned int*)(const void*)src,
                (__attribute__((address_space(3))) unsigned int*)(void*)(Ab + ch * 512),
                16, 0, 0);
        }
    };
    auto stageB = [&](int t, int kk) {
        int k32 = (t << 6) + (kk << 5);
        unsigned short* Bb = &Bs[t & 1][kk][0];
#pragma unroll
        for (int j = 0; j < 2; ++j) {
            int ch = w8 + 8 * j;
            const unsigned short* src = wmb
                + (size_t)(col0 + ch * 16 + lrow) * fin_tot + k32 + lk8;
            __builtin_amdgcn_global_load_lds(
                (const __attribute__((address_space(1))) unsigned int*)(const void*)src,
                (__attribute__((address_space(3))) unsigned int*)(void*)(Bb + ch * 512),
                16, 0, 0);
        }
    };

    auto readA = [&](const unsigned short* Ak, int im0, short8* d4) {
        dsr4(Ak + im0 * 512 + roff, d4);
    };
    auto readB = [&](const unsigned short* Bk, short8* d4) {
        dsr4(Bk + roff, d4);
    };
    auto mfma16 = [&](int im0, short8* af, short8* bv) {
#pragma unroll
        for (int q = 0; q < 4; ++q)
#pragma unroll
            for (int in = 0; in < 4; ++in)
                acc[im0 + q][in] = __builtin_amdgcn_mfma_f32_16x16x32_bf16(
                    af[q], bv[in], acc[im0 + q][in], 0, 0, 0);
    };

    short8 afX[4], afY[4], bvA[4], bvB[4];

    // ---- prologue: stage tile 0; pre-read phase-0 operands ----
    stageA(0, 0); stageB(0, 0); stageA(0, 1); stageB(0, 1);
    asm volatile("s_waitcnt vmcnt(4)");
    __builtin_amdgcn_s_barrier();
    readA(&As[0][0][wm * 4096], 0, afX);
    readB(&Bs[0][0][wn * 2048], bvA);

    // ---- main loop: 4 phases per K-tile, read-ahead by one phase ----
    for (int t = 0; t < nt - 1; ++t) {
        const int cur = t & 1, nxt = cur ^ 1;
        const unsigned short* A0  = &As[cur][0][wm * 4096];
        const unsigned short* A1  = &As[cur][1][wm * 4096];
        const unsigned short* B1p = &Bs[cur][1][wn * 2048];
        const unsigned short* A0n = &As[nxt][0][wm * 4096];
        const unsigned short* B0n = &Bs[nxt][0][wn * 2048];

        // phase 0: mfma(im0-3, kk0); read-ahead A kk0 hi
        stageA(t + 1, 0);
        readA(A0, 4, afY);
        __builtin_amdgcn_s_barrier();
        __builtin_amdgcn_sched_barrier(0);
        asm volatile("s_waitcnt lgkmcnt(4)");
        __builtin_amdgcn_sched_barrier(0);
        __builtin_amdgcn_s_setprio(1);
        mfma16(0, afX, bvA);
        __builtin_amdgcn_s_setprio(0);
        __builtin_amdgcn_s_barrier();

        // phase 1: mfma(im4-7, kk0); read-ahead A kk1 lo + B kk1
        stageB(t + 1, 0);
        asm volatile("s_waitcnt vmcnt(4)");
        __builtin_amdgcn_s_barrier();
        readA(A1, 0, afX);
        readB(B1p, bvB);
        __builtin_amdgcn_sched_barrier(0);
        asm volatile("s_waitcnt lgkmcnt(8)");
        __builtin_amdgcn_sched_barrier(0);
        __builtin_amdgcn_s_setprio(1);
        mfma16(4, afY, bvA);
        __builtin_amdgcn_s_setprio(0);
        __builtin_amdgcn_s_barrier();

        // phase 2: mfma(im0-3, kk1); read-ahead A kk1 hi
        stageA(t + 1, 1);
        readA(A1, 4, afY);
        __builtin_amdgcn_s_barrier();
        __builtin_amdgcn_sched_barrier(0);
        asm volatile("s_waitcnt lgkmcnt(4)");
        __builtin_amdgcn_sched_barrier(0);
        __builtin_amdgcn_s_setprio(1);
        mfma16(0, afX, bvB);
        __builtin_amdgcn_s_setprio(0);
        __builtin_amdgcn_s_barrier();

        // phase 3: mfma(im4-7, kk1); read-ahead next tile kk0 lo + B
        stageB(t + 1, 1);
        asm volatile("s_waitcnt vmcnt(4)");
        __builtin_amdgcn_s_barrier();
        readA(A0n, 0, afX);
        readB(B0n, bvA);
        __builtin_amdgcn_sched_barrier(0);
        asm volatile("s_waitcnt lgkmcnt(8)");
        __builtin_amdgcn_sched_barrier(0);
        __builtin_amdgcn_s_setprio(1);
        mfma16(4, afY, bvB);
        __builtin_amdgcn_s_setprio(0);
        __builtin_amdgcn_s_barrier();
    }

    // ---- final tile: no staging ----
    {
        const int cur = (nt - 1) & 1;
        const unsigned short* A0  = &As[cur][0][wm * 4096];
        const unsigned short* A1  = &As[cur][1][wm * 4096];
        const unsigned short* B1p = &Bs[cur][1][wn * 2048];

        readA(A0, 4, afY);
        __builtin_amdgcn_sched_barrier(0);
        asm volatile("s_waitcnt lgkmcnt(4)");
        __builtin_amdgcn_sched_barrier(0);
        __builtin_amdgcn_s_setprio(1);
        mfma16(0, afX, bvA);
        __builtin_amdgcn_s_setprio(0);

        asm volatile("s_waitcnt vmcnt(0)");   // kk1 halves of final tile landed
        __builtin_amdgcn_s_barrier();

        readA(A1, 0, afX);
        readB(B1p, bvB);
        __builtin_amdgcn_sched_barrier(0);
        asm volatile("s_waitcnt lgkmcnt(8)");
        __builtin_amdgcn_sched_barrier(0);
        __builtin_amdgcn_s_setprio(1);
        mfma16(4, afY, bvA);
        __builtin_amdgcn_s_setprio(0);

        readA(A1, 4, afY);
        __builtin_amdgcn_sched_barrier(0);
        asm volatile("s_waitcnt lgkmcnt(4)");
        __builtin_amdgcn_sched_barrier(0);
        __builtin_amdgcn_s_setprio(1);
        mfma16(0, afX, bvB);
        __builtin_amdgcn_s_setprio(0);

        __builtin_amdgcn_sched_barrier(0);
        asm volatile("s_waitcnt lgkmcnt(0)");
        __builtin_amdgcn_sched_barrier(0);
        __builtin_amdgcn_s_setprio(1);
        mfma16(4, afY, bvB);
        __builtin_amdgcn_s_setprio(0);
    }

    // epilogue: C/D layout col=lane&15, row=quad*4+reg; leaky + store
#pragma unroll
    for (int im = 0; im < 8; ++im) {
#pragma unroll
        for (int in = 0; in < 4; ++in) {
#pragma unroll
            for (int reg = 0; reg < 4; ++reg) {
                int r = wm * 128 + im * 16 + fq * 4 + reg;
                int col = wn * 64 + in * 16 + fr;
                float v = acc[im][in][reg];
                if (act) v = v > 0.f ? v : 0.01f * v;
                size_t off = (tokbase + row0 + r) * fout + col0 + col;
                if (outb) outb[off] = f2bf(v);
                else      outf[off] = v;
            }
        }
    }
}

// ---------------------------------------------------------------------------
// Launch. Workspace: gw0T 64K | gw1T 8K | xz 16.8M | coef 0.5M | cpad 2M |
// actB 33.6M; then adaptive gb tier for wmT (+actA at gb=32).
// ---------------------------------------------------------------------------
extern "C" void kernel_launch(void* const* d_in, const int* in_sizes, int n_in,
                              void* d_out, int out_size, void* d_ws, size_t ws_size,
                              hipStream_t stream)
{
    const float* z = (const float*)d_in[0];
    const float* c = (const float*)d_in[1];
    const float* w[5]  = {(const float*)d_in[2], (const float*)d_in[4],
                          (const float*)d_in[6], (const float*)d_in[8],
                          (const float*)d_in[10]};
    const float* bs[5] = {(const float*)d_in[3], (const float*)d_in[5],
                          (const float*)d_in[7], (const float*)d_in[9],
                          (const float*)d_in[11]};
    const float* gw0 = (const float*)d_in[12]; const float* gb0 = (const float*)d_in[13];
    const float* gw1 = (const float*)d_in[14]; const float* gb1 = (const float*)d_in[15];
    const float* gw2 = (const float*)d_in[16]; const float* gb2 = (const float*)d_in[17];

    const size_t g0t_b  = (size_t)GATEH * INPUT_ * 2;   // 64 KB
    const size_t g1t_b  = (size_t)GATEH * GATEH * 2;    // 8 KB
    const size_t xz_b   = (size_t)NTOK * INPUT_ * 2;
    const size_t coef_b = (size_t)NTOK * E_ * 4;
    const size_t cpad_b = (size_t)NTOK * KTAIL * 2;
    const size_t act_b  = (size_t)NTOK * HIDDEN * 2;
    const size_t wmun   = (size_t)(INTER_ + KTAIL) * HIDDEN * 2;  // per-batch max

    char* p = (char*)d_ws;
    unsigned short* gw0T  = (unsigned short*)p;  p += g0t_b;
    unsigned short* gw1T  = (unsigned short*)p;  p += g1t_b;
    unsigned short* xzb   = (unsigned short*)p;  p += xz_b;
    float*          coef  = (float*)p;           p += coef_b;
    unsigned short* cpad  = (unsigned short*)p;  p += cpad_b;
    unsigned short* actB  = (unsigned short*)p;  p += act_b;

    size_t base = g0t_b + g1t_b + xz_b + coef_b + cpad_b + act_b;
    size_t avail = (ws_size > base) ? ws_size - base : 0;

    int gb;
    unsigned short* actA;
    unsigned short* wmT;
    if (avail >= act_b + 32 * wmun) {
        gb = 32; actA = (unsigned short*)p; p += act_b; wmT = (unsigned short*)p;
    } else {
        actA = (unsigned short*)d_out;
        wmT  = (unsigned short*)p;
        gb = 1;
        for (int g = 16; g >= 2; g >>= 1)
            if (avail >= (size_t)g * wmun) { gb = g; break; }
    }

    wprep_kernel<<<(GATEH * (INPUT_ + GATEH) + 255) / 256, 256, 0, stream>>>(
        gw0, gw1, gw0T, gw1T);
    gate_kernel<<<NTOK / 64, 256, 0, stream>>>(
        z, c, gb0, gb1, gw2, gb2, gw0T, gw1T, coef, cpad, xzb);

    struct L { int fin, fout, act; const unsigned short* in; unsigned short* outb; };
    L Ls[5] = {
        {INPUT_, HIDDEN, 1, actB /*unused*/, actA},
        {INTER_, HIDDEN, 1, actA, actB},
        {INTER_, HIDDEN, 1, actB, actA},
        {INTER_, HIDDEN, 1, actA, actB},
        {INTER_, OUTD,   0, actB, 0},
    };

    for (int Li = 0; Li < 5; ++Li) {
        int fin = Ls[Li].fin, fout = Ls[Li].fout;
        int nblk = (fin / MI) * (fout / MO);
        for (int g = 0; g < B_; g += gb) {
            mixT_kernel<<<nblk, 256, 0, stream>>>(
                w[Li], bs[Li], coef, wmT, fin, fout, gb, g);
            gemm_kernel<<<dim3(fout / 256, T_ / 256, gb), 512, 0, stream>>>(
                xzb, Ls[Li].in, wmT, cpad,
                (float*)d_out, Ls[Li].outb, fin + KTAIL, fout, Ls[Li].act, g);
        }
    }
}

// Round 5
// 594.279 us; speedup vs baseline: 1.2069x; 1.0254x over previous
//
#include <hip/hip_runtime.h>
#include <math.h>

// Problem constants
#define B_     32
#define T_     512
#define LATENT 64
#define COND   448
#define HIDDEN 1024
#define OUTD   512
#define E_     8
#define INPUT_ 512     // LATENT + COND
#define INTER_ 1536    // LATENT + COND + HIDDEN
#define GATEH  64
#define NTOK   (B_ * T_)   // 16384
#define KTAIL  64          // bias-mix folded into K as one extra 64-chunk (BK=64 aligned)

typedef __attribute__((ext_vector_type(8))) short short8;   // bf16x8 MFMA A/B frag
typedef __attribute__((ext_vector_type(4))) float f32x4;    // MFMA C/D frag

typedef __attribute__((address_space(3))) const unsigned short* lds_cptr;

static __device__ __forceinline__ unsigned short f2bf(float x) {
    unsigned u = __float_as_uint(x);
    u += 0x7fffu + ((u >> 16) & 1u);
    return (unsigned short)(u >> 16);
}

// 4x ds_read_b128 at offsets 0/1024/2048/3072 from p, as ONE inline-asm unit.
// Opaque to the compiler's waitcnt pass: no auto-inserted vmcnt/lgkm drains.
// lgkm accounting is owned by the caller (counted s_waitcnt + sched_barrier).
static __device__ __forceinline__ void dsr4(const unsigned short* p, short8* d) {
    lds_cptr q = (lds_cptr)p;
    asm volatile("ds_read_b128 %0, %4 offset:0\n\t"
                 "ds_read_b128 %1, %4 offset:1024\n\t"
                 "ds_read_b128 %2, %4 offset:2048\n\t"
                 "ds_read_b128 %3, %4 offset:3072"
                 : "=&v"(d[0]), "=&v"(d[1]), "=&v"(d[2]), "=&v"(d[3])
                 : "v"(q));
}

// ---------------------------------------------------------------------------
// wprep: transpose gate weights to bf16 [n][k] rows for MFMA B-operands.
// ---------------------------------------------------------------------------
__global__ __launch_bounds__(256) void wprep_kernel(
    const float* __restrict__ gw0, const float* __restrict__ gw1,
    unsigned short* __restrict__ gw0T, unsigned short* __restrict__ gw1T)
{
    int idx = blockIdx.x * 256 + threadIdx.x;
    if (idx < GATEH * INPUT_) {
        int n = idx >> 9, k = idx & 511;
        gw0T[n * INPUT_ + k] = f2bf(gw0[k * GATEH + n]);
    } else {
        int i2 = idx - GATEH * INPUT_;
        if (i2 < GATEH * GATEH) {
            int n = i2 >> 6, k = i2 & 63;
            gw1T[n * GATEH + k] = f2bf(gw1[k * GATEH + n]);
        }
    }
}

// ---------------------------------------------------------------------------
// Gate (MFMA): 64 tokens/block, 256 threads (4 waves).
// ---------------------------------------------------------------------------
__global__ __launch_bounds__(256) void gate_kernel(
    const float* __restrict__ z, const float* __restrict__ c,
    const float* __restrict__ gb0,
    const float* __restrict__ gb1,
    const float* __restrict__ gw2, const float* __restrict__ gb2,
    const unsigned short* __restrict__ gw0T,
    const unsigned short* __restrict__ gw1T,
    float* __restrict__ coef, unsigned short* __restrict__ coefpad,
    unsigned short* __restrict__ xzb)
{
    __shared__ unsigned short Hb[GATEH][72];   // g0 out, bf16, pad->2-way free
    __shared__ float H2[GATEH][65];            // g1 out, fp32
    __shared__ float sLg[GATEH][E_];           // logits

    const int tid = threadIdx.x;
    const int lane = tid & 63;
    const int wv = tid >> 6;
    const int tok0 = blockIdx.x * 64;

    // ---- phase 0: z|c -> xz bf16 ----
#pragma unroll
    for (int i = 0; i < 4; ++i) {              // z: 64 tok x 64
        int idx = i * 256 + tid;
        int tr = idx >> 4, c4 = (idx & 15) * 4;
        float4 v = *(const float4*)(z + ((size_t)(tok0 + tr) * LATENT) + c4);
        ushort4 o = {f2bf(v.x), f2bf(v.y), f2bf(v.z), f2bf(v.w)};
        *(ushort4*)(xzb + (size_t)(tok0 + tr) * INPUT_ + c4) = o;
    }
#pragma unroll
    for (int i = 0; i < 28; ++i) {             // c: 64 tok x 448
        int idx = i * 256 + tid;
        int tr = idx / 112, c4 = (idx % 112) * 4;
        float4 v = *(const float4*)(c + ((size_t)(tok0 + tr) * COND) + c4);
        ushort4 o = {f2bf(v.x), f2bf(v.y), f2bf(v.z), f2bf(v.w)};
        *(ushort4*)(xzb + (size_t)(tok0 + tr) * INPUT_ + LATENT + c4) = o;
    }
    __threadfence_block();
    __syncthreads();

    const int fr = lane & 15, fq = lane >> 4;
    const int wm0 = (wv & 1) * 32, wn0 = (wv >> 1) * 32;

    // ---- g0 MFMA ----
    f32x4 acc[2][2];
#pragma unroll
    for (int im = 0; im < 2; ++im)
#pragma unroll
        for (int in = 0; in < 2; ++in) acc[im][in] = (f32x4){0.f,0.f,0.f,0.f};

    for (int k0 = 0; k0 < INPUT_; k0 += 32) {
        short8 af[2], bf[2];
#pragma unroll
        for (int im = 0; im < 2; ++im)
            af[im] = *(const short8*)(xzb + (size_t)(tok0 + wm0 + im*16 + fr) * INPUT_
                                          + k0 + fq * 8);
#pragma unroll
        for (int in = 0; in < 2; ++in)
            bf[in] = *(const short8*)(gw0T + (size_t)(wn0 + in*16 + fr) * INPUT_
                                           + k0 + fq * 8);
#pragma unroll
        for (int im = 0; im < 2; ++im)
#pragma unroll
            for (int in = 0; in < 2; ++in)
                acc[im][in] = __builtin_amdgcn_mfma_f32_16x16x32_bf16(
                    af[im], bf[in], acc[im][in], 0, 0, 0);
    }
    // C layout: col=lane&15, row=(lane>>4)*4+reg
#pragma unroll
    for (int im = 0; im < 2; ++im)
#pragma unroll
        for (int in = 0; in < 2; ++in)
#pragma unroll
            for (int reg = 0; reg < 4; ++reg) {
                int m = wm0 + im*16 + fq*4 + reg;
                int n = wn0 + in*16 + fr;
                float h = acc[im][in][reg] + gb0[n];
                h = h > 0.f ? h : 0.01f * h;
                Hb[m][n] = f2bf(h);
            }
    __syncthreads();

    // ---- g1 MFMA ----
    f32x4 a2[2][2];
#pragma unroll
    for (int im = 0; im < 2; ++im)
#pragma unroll
        for (int in = 0; in < 2; ++in) a2[im][in] = (f32x4){0.f,0.f,0.f,0.f};
#pragma unroll
    for (int k0 = 0; k0 < GATEH; k0 += 32) {
        short8 af[2], bf[2];
#pragma unroll
        for (int im = 0; im < 2; ++im)
            af[im] = *(const short8*)(&Hb[wm0 + im*16 + fr][k0 + fq*8]);
#pragma unroll
        for (int in = 0; in < 2; ++in)
            bf[in] = *(const short8*)(gw1T + (size_t)(wn0 + in*16 + fr) * GATEH
                                           + k0 + fq * 8);
#pragma unroll
        for (int im = 0; im < 2; ++im)
#pragma unroll
            for (int in = 0; in < 2; ++in)
                a2[im][in] = __builtin_amdgcn_mfma_f32_16x16x32_bf16(
                    af[im], bf[in], a2[im][in], 0, 0, 0);
    }
#pragma unroll
    for (int im = 0; im < 2; ++im)
#pragma unroll
        for (int in = 0; in < 2; ++in)
#pragma unroll
            for (int reg = 0; reg < 4; ++reg) {
                int m = wm0 + im*16 + fq*4 + reg;
                int n = wn0 + in*16 + fr;
                float h = a2[im][in][reg] + gb1[n];
                H2[m][n] = h > 0.f ? h : 0.01f * h;
            }
    __syncthreads();

    // ---- g2 (vector): thread -> (tok = tid>>2, 2 experts) ----
    {
        int tok = tid >> 2, e0 = (tid & 3) * 2;
        float l0 = gb2[e0], l1 = gb2[e0 + 1];
#pragma unroll
        for (int i = 0; i < GATEH; ++i) {
            float h = H2[tok][i];
            l0 = fmaf(h, gw2[i * E_ + e0], l0);
            l1 = fmaf(h, gw2[i * E_ + e0 + 1], l1);
        }
        sLg[tok][e0] = l0; sLg[tok][e0 + 1] = l1;
    }
    __syncthreads();

    // ---- softmax + outputs: one thread per token ----
    if (tid < 64) {
        int token = tok0 + tid;
        float lg[E_], m = -1e30f, s = 0.f;
#pragma unroll
        for (int e = 0; e < E_; ++e) { lg[e] = sLg[tid][e]; m = fmaxf(m, lg[e]); }
#pragma unroll
        for (int e = 0; e < E_; ++e) { lg[e] = expf(lg[e] - m); s += lg[e]; }
        float inv = 1.f / s;
        unsigned short pad[KTAIL];
#pragma unroll
        for (int e = 0; e < E_; ++e) {
            float cv = lg[e] * inv;
            coef[(size_t)token * E_ + e] = cv;
            pad[e] = f2bf(cv);
        }
#pragma unroll
        for (int j = E_; j < KTAIL; ++j) pad[j] = 0;
#pragma unroll
        for (int q = 0; q < KTAIL / 4; ++q)
            *(ushort4*)(coefpad + (size_t)token * KTAIL + q * 4) =
                *(const ushort4*)&pad[q * 4];
    }
}

// ---------------------------------------------------------------------------
// Transpose-mix v3: wmT[b][o][i] = bf16( sum_e coef0[b][e] * w[e][i][o] ).
// Tile MI2=64 x MO2=32 so every wmT write is a FULL 128-byte line from one
// block (8 threads x 16 B contiguous per o-row; i0*2 and fin*2 are 128 B
// aligned). v2's MI=32 wrote 64 B half-lines whose other half belonged to a
// different block -> systematic partial-line HBM writes (~2x write cost).
// sW pad 33 keeps LDS ops <=2-way; scalar LDS ops (no misaligned float4).
// K-tail rows i in [fin, fin+8): bias[e][o]; [fin+8, fin+64): 0.
// ---------------------------------------------------------------------------
#define MI2 64
#define MO2 32

__global__ __launch_bounds__(256) void mixT_kernel(
    const float* __restrict__ w,          // (E, fin, fout) fp32
    const float* __restrict__ bias,       // (E, fout) fp32
    const float* __restrict__ coef,       // (NTOK, 8)
    unsigned short* __restrict__ wmT,     // (gb, fout, fin+64) bf16
    int fin, int fout, int gb, int batch0)
{
    __shared__ float sW[E_][MI2][33];
    __shared__ float sC[B_][E_];
    const int t = threadIdx.x;
    const int fin_tot = fin + KTAIL;
    const int nbi = fin / MI2;
    const int i0 = (blockIdx.x % nbi) * MI2;
    const int o0 = (blockIdx.x / nbi) * MO2;

    if (t < gb * E_)
        sC[t >> 3][t & 7] = coef[(size_t)(batch0 + (t >> 3)) * T_ * E_ + (t & 7)];

    // staging: 8 e x 64 i x 8 float4 = 4096 float4 / 256 thr = 16 iters
#pragma unroll
    for (int r = 0; r < 16; ++r) {
        int idx = r * 256 + t;
        int o4 = idx & 7;
        int i  = (idx >> 3) & 63;
        int e  = idx >> 9;
        float4 v = *(const float4*)(w + (size_t)e * fin * fout
                                      + (size_t)(i0 + i) * fout + o0 + o4 * 4);
        sW[e][i][o4 * 4 + 0] = v.x;
        sW[e][i][o4 * 4 + 1] = v.y;
        sW[e][i][o4 * 4 + 2] = v.z;
        sW[e][i][o4 * 4 + 3] = v.w;
    }
    __syncthreads();

    const int o  = t >> 3;          // 0..31
    const int i8 = (t & 7) * 8;     // 0..56

    // cache this thread's 8x8 slice in registers (<=2-way LDS reads)
    float rw[E_][8];
#pragma unroll
    for (int e = 0; e < E_; ++e)
#pragma unroll
        for (int j = 0; j < 8; ++j)
            rw[e][j] = sW[e][i8 + j][o];

    for (int b = 0; b < gb; ++b) {
        float v[8];
#pragma unroll
        for (int j = 0; j < 8; ++j) v[j] = 0.f;
#pragma unroll
        for (int e = 0; e < E_; ++e) {
            float cc = sC[b][e];
#pragma unroll
            for (int j = 0; j < 8; ++j)
                v[j] = fmaf(cc, rw[e][j], v[j]);
        }
        unsigned short u[8];
#pragma unroll
        for (int j = 0; j < 8; ++j) u[j] = f2bf(v[j]);
        *(int4*)(wmT + ((size_t)b * fout + o0 + o) * fin_tot + i0 + i8) = *(const int4*)u;
    }

    if (i0 == 0) {
        const int jj = t & 7;       // 8 threads cover the 128 B tail per o-row
        unsigned short u[8];
#pragma unroll
        for (int q = 0; q < 8; ++q)
            u[q] = (jj == 0) ? f2bf(bias[(size_t)q * fout + o0 + o]) : 0;
        for (int b = 0; b < gb; ++b) {
            size_t rb = ((size_t)b * fout + o0 + o) * fin_tot + fin;
            *(int4*)(wmT + rb + jj * 8) = *(const int4*)u;
        }
    }
}

// ---------------------------------------------------------------------------
// MFMA GEMM, v5 (unchanged from R4): 8-phase, read-ahead, counted
// vmcnt(4)/lgkmcnt(4|8) never 0 in main loop; inline-asm ds_read_b128
// (opaque to compiler waitcnt pass); sched_barrier(0) pins per rule #18.
// ---------------------------------------------------------------------------
__global__ __launch_bounds__(512, 2) void gemm_kernel(
    const unsigned short* __restrict__ xz,      // (NTOK, 512) bf16
    const unsigned short* __restrict__ prev,    // (NTOK, 1024) bf16
    const unsigned short* __restrict__ wmT,     // (gb, fout, fin_tot) bf16
    const unsigned short* __restrict__ coefpad, // (NTOK, 64) bf16
    float* __restrict__ outf,                   // fp32 out (layer 4)
    unsigned short* __restrict__ outb,          // bf16 out (layers 0-3), or null
    int fin_tot, int fout, int act, int batch0)
{
    __shared__ __align__(16) unsigned short As[2][2][8192];   // 64 KiB
    __shared__ __align__(16) unsigned short Bs[2][2][8192];   // 64 KiB

    const int tid = threadIdx.x;
    const int lane = tid & 63;
    const int w8 = tid >> 6;          // wave 0..7
    const int wm = w8 & 1;            // M half
    const int wn = w8 >> 1;           // N quarter

    // ---- batch-clustered XCD remap (bijective when 8 | nwg) ----
    const int nx = gridDim.x;         // fout/256
    int bx = blockIdx.x, by = blockIdx.y, bz = blockIdx.z;
    {
        int nwg = nx * 2 * gridDim.z;
        if ((nwg & 7) == 0) {
            int f = blockIdx.x + nx * (blockIdx.y + 2 * blockIdx.z);
            int q = nwg >> 3;
            int wk = (f & 7) * q + (f >> 3);   // XCD (f&7) owns contiguous chunk
            int bpb = nx * 2;                  // blocks per batch
            bz = wk / bpb;
            int r = wk - bz * bpb;
            by = r / nx;
            bx = r - by * nx;
        }
    }

    const int row0 = by * 256;
    const int col0 = bx * 256;
    const size_t tokbase = (size_t)(batch0 + bz) * T_;
    const unsigned short* wmb = wmT + (size_t)bz * fin_tot * fout;

    // staging lane geometry (matches global_load_lds linear lane scatter)
    const int lrow = lane >> 2;                               // row in 16-row chunk
    const int lk8  = (((lane & 3) ^ ((lane >> 3) & 3)) * 8);  // swizzled k offset
    // frag-read geometry
    const int fr = lane & 15, fq = lane >> 4;
    const int koff = (fq ^ ((fr >> 1) & 3)) * 8;              // swizzled read offset
    const int roff = fr * 32 + koff;
    const int ktail0 = fin_tot - KTAIL;
    const int nt = fin_tot >> 6;                              // 9 or 25 K-tiles

    f32x4 acc[8][4];
#pragma unroll
    for (int im = 0; im < 8; ++im)
#pragma unroll
        for (int in = 0; in < 4; ++in)
            acc[im][in] = (f32x4){0.f, 0.f, 0.f, 0.f};

    // stage one A/B half-tile (256 rows x 32 k, 16 KB) of K-tile t, half kk
    auto stageA = [&](int t, int kk) {
        int k32 = (t << 6) + (kk << 5);
        const unsigned short* abase; int astr, acol;
        if (k32 < INPUT_)      { abase = xz;      astr = INPUT_; acol = k32; }
        else if (k32 < ktail0) { abase = prev;    astr = HIDDEN; acol = k32 - INPUT_; }
        else                   { abase = coefpad; astr = KTAIL;  acol = k32 - ktail0; }
        unsigned short* Ab = &As[t & 1][kk][0];
#pragma unroll
        for (int j = 0; j < 2; ++j) {
            int ch = w8 + 8 * j;              // chunk 0..15 (wave-uniform)
            const unsigned short* src = abase
                + (tokbase + row0 + ch * 16 + lrow) * (size_t)astr + acol + lk8;
            __builtin_amdgcn_global_load_lds(
                (const __attribute__((address_space(1))) unsigned int*)(const void*)src,
                (__attribute__((address_space(3))) unsigned int*)(void*)(Ab + ch * 512),
                16, 0, 0);
        }
    };
    auto stageB = [&](int t, int kk) {
        int k32 = (t << 6) + (kk << 5);
        unsigned short* Bb = &Bs[t & 1][kk][0];
#pragma unroll
        for (int j = 0; j < 2; ++j) {
            int ch = w8 + 8 * j;
            const unsigned short* src = wmb
                + (size_t)(col0 + ch * 16 + lrow) * fin_tot + k32 + lk8;
            __builtin_amdgcn_global_load_lds(
                (const __attribute__((address_space(1))) unsigned int*)(const void*)src,
                (__attribute__((address_space(3))) unsigned int*)(void*)(Bb + ch * 512),
                16, 0, 0);
        }
    };

    auto readA = [&](const unsigned short* Ak, int im0, short8* d4) {
        dsr4(Ak + im0 * 512 + roff, d4);
    };
    auto readB = [&](const unsigned short* Bk, short8* d4) {
        dsr4(Bk + roff, d4);
    };
    auto mfma16 = [&](int im0, short8* af, short8* bv) {
#pragma unroll
        for (int q = 0; q < 4; ++q)
#pragma unroll
            for (int in = 0; in < 4; ++in)
                acc[im0 + q][in] = __builtin_amdgcn_mfma_f32_16x16x32_bf16(
                    af[q], bv[in], acc[im0 + q][in], 0, 0, 0);
    };

    short8 afX[4], afY[4], bvA[4], bvB[4];

    // ---- prologue: stage tile 0; pre-read phase-0 operands ----
    stageA(0, 0); stageB(0, 0); stageA(0, 1); stageB(0, 1);
    asm volatile("s_waitcnt vmcnt(4)");
    __builtin_amdgcn_s_barrier();
    readA(&As[0][0][wm * 4096], 0, afX);
    readB(&Bs[0][0][wn * 2048], bvA);

    // ---- main loop: 4 phases per K-tile, read-ahead by one phase ----
    for (int t = 0; t < nt - 1; ++t) {
        const int cur = t & 1, nxt = cur ^ 1;
        const unsigned short* A0  = &As[cur][0][wm * 4096];
        const unsigned short* A1  = &As[cur][1][wm * 4096];
        const unsigned short* B1p = &Bs[cur][1][wn * 2048];
        const unsigned short* A0n = &As[nxt][0][wm * 4096];
        const unsigned short* B0n = &Bs[nxt][0][wn * 2048];

        // phase 0: mfma(im0-3, kk0); read-ahead A kk0 hi
        stageA(t + 1, 0);
        readA(A0, 4, afY);
        __builtin_amdgcn_s_barrier();
        __builtin_amdgcn_sched_barrier(0);
        asm volatile("s_waitcnt lgkmcnt(4)");
        __builtin_amdgcn_sched_barrier(0);
        __builtin_amdgcn_s_setprio(1);
        mfma16(0, afX, bvA);
        __builtin_amdgcn_s_setprio(0);
        __builtin_amdgcn_s_barrier();

        // phase 1: mfma(im4-7, kk0); read-ahead A kk1 lo + B kk1
        stageB(t + 1, 0);
        asm volatile("s_waitcnt vmcnt(4)");
        __builtin_amdgcn_s_barrier();
        readA(A1, 0, afX);
        readB(B1p, bvB);
        __builtin_amdgcn_sched_barrier(0);
        asm volatile("s_waitcnt lgkmcnt(8)");
        __builtin_amdgcn_sched_barrier(0);
        __builtin_amdgcn_s_setprio(1);
        mfma16(4, afY, bvA);
        __builtin_amdgcn_s_setprio(0);
        __builtin_amdgcn_s_barrier();

        // phase 2: mfma(im0-3, kk1); read-ahead A kk1 hi
        stageA(t + 1, 1);
        readA(A1, 4, afY);
        __builtin_amdgcn_s_barrier();
        __builtin_amdgcn_sched_barrier(0);
        asm volatile("s_waitcnt lgkmcnt(4)");
        __builtin_amdgcn_sched_barrier(0);
        __builtin_amdgcn_s_setprio(1);
        mfma16(0, afX, bvB);
        __builtin_amdgcn_s_setprio(0);
        __builtin_amdgcn_s_barrier();

        // phase 3: mfma(im4-7, kk1); read-ahead next tile kk0 lo + B
        stageB(t + 1, 1);
        asm volatile("s_waitcnt vmcnt(4)");
        __builtin_amdgcn_s_barrier();
        readA(A0n, 0, afX);
        readB(B0n, bvA);
        __builtin_amdgcn_sched_barrier(0);
        asm volatile("s_waitcnt lgkmcnt(8)");
        __builtin_amdgcn_sched_barrier(0);
        __builtin_amdgcn_s_setprio(1);
        mfma16(4, afY, bvB);
        __builtin_amdgcn_s_setprio(0);
        __builtin_amdgcn_s_barrier();
    }

    // ---- final tile: no staging ----
    {
        const int cur = (nt - 1) & 1;
        const unsigned short* A0  = &As[cur][0][wm * 4096];
        const unsigned short* A1  = &As[cur][1][wm * 4096];
        const unsigned short* B1p = &Bs[cur][1][wn * 2048];

        readA(A0, 4, afY);
        __builtin_amdgcn_sched_barrier(0);
        asm volatile("s_waitcnt lgkmcnt(4)");
        __builtin_amdgcn_sched_barrier(0);
        __builtin_amdgcn_s_setprio(1);
        mfma16(0, afX, bvA);
        __builtin_amdgcn_s_setprio(0);

        asm volatile("s_waitcnt vmcnt(0)");   // kk1 halves of final tile landed
        __builtin_amdgcn_s_barrier();

        readA(A1, 0, afX);
        readB(B1p, bvB);
        __builtin_amdgcn_sched_barrier(0);
        asm volatile("s_waitcnt lgkmcnt(8)");
        __builtin_amdgcn_sched_barrier(0);
        __builtin_amdgcn_s_setprio(1);
        mfma16(4, afY, bvA);
        __builtin_amdgcn_s_setprio(0);

        readA(A1, 4, afY);
        __builtin_amdgcn_sched_barrier(0);
        asm volatile("s_waitcnt lgkmcnt(4)");
        __builtin_amdgcn_sched_barrier(0);
        __builtin_amdgcn_s_setprio(1);
        mfma16(0, afX, bvB);
        __builtin_amdgcn_s_setprio(0);

        __builtin_amdgcn_sched_barrier(0);
        asm volatile("s_waitcnt lgkmcnt(0)");
        __builtin_amdgcn_sched_barrier(0);
        __builtin_amdgcn_s_setprio(1);
        mfma16(4, afY, bvB);
        __builtin_amdgcn_s_setprio(0);
    }

    // epilogue: C/D layout col=lane&15, row=quad*4+reg; leaky + store
#pragma unroll
    for (int im = 0; im < 8; ++im) {
#pragma unroll
        for (int in = 0; in < 4; ++in) {
#pragma unroll
            for (int reg = 0; reg < 4; ++reg) {
                int r = wm * 128 + im * 16 + fq * 4 + reg;
                int col = wn * 64 + in * 16 + fr;
                float v = acc[im][in][reg];
                if (act) v = v > 0.f ? v : 0.01f * v;
                size_t off = (tokbase + row0 + r) * fout + col0 + col;
                if (outb) outb[off] = f2bf(v);
                else      outf[off] = v;
            }
        }
    }
}

// ---------------------------------------------------------------------------
// Launch. Workspace: gw0T 64K | gw1T 8K | xz 16.8M | coef 0.5M | cpad 2M |
// actB 33.6M; then adaptive gb tier for wmT (+actA at gb=32).
// ---------------------------------------------------------------------------
extern "C" void kernel_launch(void* const* d_in, const int* in_sizes, int n_in,
                              void* d_out, int out_size, void* d_ws, size_t ws_size,
                              hipStream_t stream)
{
    const float* z = (const float*)d_in[0];
    const float* c = (const float*)d_in[1];
    const float* w[5]  = {(const float*)d_in[2], (const float*)d_in[4],
                          (const float*)d_in[6], (const float*)d_in[8],
                          (const float*)d_in[10]};
    const float* bs[5] = {(const float*)d_in[3], (const float*)d_in[5],
                          (const float*)d_in[7], (const float*)d_in[9],
                          (const float*)d_in[11]};
    const float* gw0 = (const float*)d_in[12]; const float* gb0 = (const float*)d_in[13];
    const float* gw1 = (const float*)d_in[14]; const float* gb1 = (const float*)d_in[15];
    const float* gw2 = (const float*)d_in[16]; const float* gb2 = (const float*)d_in[17];

    const size_t g0t_b  = (size_t)GATEH * INPUT_ * 2;   // 64 KB
    const size_t g1t_b  = (size_t)GATEH * GATEH * 2;    // 8 KB
    const size_t xz_b   = (size_t)NTOK * INPUT_ * 2;
    const size_t coef_b = (size_t)NTOK * E_ * 4;
    const size_t cpad_b = (size_t)NTOK * KTAIL * 2;
    const size_t act_b  = (size_t)NTOK * HIDDEN * 2;
    const size_t wmun   = (size_t)(INTER_ + KTAIL) * HIDDEN * 2;  // per-batch max

    char* p = (char*)d_ws;
    unsigned short* gw0T  = (unsigned short*)p;  p += g0t_b;
    unsigned short* gw1T  = (unsigned short*)p;  p += g1t_b;
    unsigned short* xzb   = (unsigned short*)p;  p += xz_b;
    float*          coef  = (float*)p;           p += coef_b;
    unsigned short* cpad  = (unsigned short*)p;  p += cpad_b;
    unsigned short* actB  = (unsigned short*)p;  p += act_b;

    size_t base = g0t_b + g1t_b + xz_b + coef_b + cpad_b + act_b;
    size_t avail = (ws_size > base) ? ws_size - base : 0;

    int gb;
    unsigned short* actA;
    unsigned short* wmT;
    if (avail >= act_b + 32 * wmun) {
        gb = 32; actA = (unsigned short*)p; p += act_b; wmT = (unsigned short*)p;
    } else {
        actA = (unsigned short*)d_out;
        wmT  = (unsigned short*)p;
        gb = 1;
        for (int g = 16; g >= 2; g >>= 1)
            if (avail >= (size_t)g * wmun) { gb = g; break; }
    }

    wprep_kernel<<<(GATEH * (INPUT_ + GATEH) + 255) / 256, 256, 0, stream>>>(
        gw0, gw1, gw0T, gw1T);
    gate_kernel<<<NTOK / 64, 256, 0, stream>>>(
        z, c, gb0, gb1, gw2, gb2, gw0T, gw1T, coef, cpad, xzb);

    struct L { int fin, fout, act; const unsigned short* in; unsigned short* outb; };
    L Ls[5] = {
        {INPUT_, HIDDEN, 1, actB /*unused*/, actA},
        {INTER_, HIDDEN, 1, actA, actB},
        {INTER_, HIDDEN, 1, actB, actA},
        {INTER_, HIDDEN, 1, actA, actB},
        {INTER_, OUTD,   0, actB, 0},
    };

    for (int Li = 0; Li < 5; ++Li) {
        int fin = Ls[Li].fin, fout = Ls[Li].fout;
        int nblk = (fin / MI2) * (fout / MO2);
        for (int g = 0; g < B_; g += gb) {
            mixT_kernel<<<nblk, 256, 0, stream>>>(
                w[Li], bs[Li], coef, wmT, fin, fout, gb, g);
            gemm_kernel<<<dim3(fout / 256, T_ / 256, gb), 512, 0, stream>>>(
                xzb, Ls[Li].in, wmT, cpad,
                (float*)d_out, Ls[Li].outb, fin + KTAIL, fout, Ls[Li].act, g);
        }
    }
}